// Round 1
// baseline (677.258 us; speedup 1.0000x reference)
//
#include <hip/hip_runtime.h>

#define NB 8
#define NC 128

// workspace layout (float offsets)
#define OFF_FGD   0u          // 1048576 : fg downsampled  [b][c][32][32]
#define OFF_BGD   1048576u    // 1048576 : bg downsampled  [b][c][32][32]
#define OFF_BGT   2097152u    // 4194304 : bg transposed   [b][y][x][c] full-res
#define OFF_SS    6291456u    // 8192    : sum_c bgd^2     [b][32*32]
#define OFF_RNORM 6299648u    // 8192    : 1/max(norm,eps) [b][1024]
#define OFF_M     6307840u    // 8192    : softmax max     [b][1024]
#define OFF_DEN   6316032u    // 8192    : softmax denom   [b][1024]
#define OFF_EQ    6324224u    // 1024 ints
#define OFF_S0    6325504u    // 8388608 : raw scores [b][P][Q]
#define OFF_S2    14714112u   // 8388608 : fused scores / weights [b][R][T]
// total 23102720 floats = 92.4 MB

__global__ void k_down(const float* __restrict__ fg, const float* __restrict__ bg,
                       float* __restrict__ fgd, float* __restrict__ bgd) {
    int i = blockIdx.x * 256 + threadIdx.x;
    if (i >= NB * NC * 32 * 32) return;
    int x = i & 31, y = (i >> 5) & 31, c = (i >> 10) & 127, b = i >> 17;
    int src = ((b * NC + c) * 64 + 2 * y) * 64 + 2 * x;
    fgd[i] = fg[src];
    bgd[i] = bg[src];
}

// BGt[b][y][x][c] = background[b][c][y][x]
__global__ void k_tr(const float* __restrict__ bg, float* __restrict__ BGt) {
    int b = blockIdx.y, y = blockIdx.x;
    __shared__ float lds[64 * 129];
    int t = threadIdx.x;
    int xx = t & 63;
    for (int c0 = 0; c0 < NC; c0 += 4) {
        int c = c0 + (t >> 6);
        lds[xx * 129 + c] = bg[((b * NC + c) * 64 + y) * 64 + xx];
    }
    __syncthreads();
    float* dst = BGt + (b * 64 + y) * 64 * NC;
    for (int j = t; j < 64 * NC; j += 256)
        dst[j] = lds[(j >> 7) * 129 + (j & 127)];
}

__global__ void k_ss(const float* __restrict__ bgd, float* __restrict__ SS) {
    int i = blockIdx.x * 256 + threadIdx.x; // 8192
    int b = i >> 10, yx = i & 1023;
    const float* p = bgd + b * NC * 1024 + yx;
    float s = 0.f;
    for (int c = 0; c < NC; ++c) { float v = p[c * 1024]; s += v * v; }
    SS[i] = s;
}

__global__ void k_eq(const float* __restrict__ mask, int* __restrict__ eq) {
    int l = blockIdx.x * 256 + threadIdx.x;
    if (l >= 1024) return;
    int hm = l >> 5, wm = l & 31;
    int any = 0;
    for (int di = -1; di <= 1; ++di)
        for (int dj = -1; dj <= 1; ++dj) {
            int yy = hm + di, xx = wm + dj;
            if (yy >= 0 && yy < 32 && xx >= 0 && xx < 32)
                any |= (mask[(2 * yy) * 64 + 2 * xx] != 0.0f);
        }
    eq[l] = !any;
}

__global__ void k_norm(const float* __restrict__ SS, float* __restrict__ rnorm) {
    int i = blockIdx.x * 256 + threadIdx.x; // 8192
    int b = i >> 10, P = i & 1023, hb = P >> 5, wb = P & 31;
    float n2 = 0.f;
    for (int di = -1; di <= 1; ++di)
        for (int dj = -1; dj <= 1; ++dj) {
            int yy = hb + di, xx = wb + dj;
            if (yy >= 0 && yy < 32 && xx >= 0 && xx < 32)
                n2 += SS[b * 1024 + yy * 32 + xx];
        }
    rnorm[i] = 1.0f / fmaxf(sqrtf(n2), 1e-4f);
}

// s0[b][P][Q] = rnorm[b][P] * sum_{c,di,dj} fg[c,yf+di-1,xf+dj-1]*bg[c,hb+di-1,wb+dj-1]
// block: 64 P x 64 Q tile, thread = 4x4 outputs
#define CK 8
__global__ void k_score(const float* __restrict__ fgd, const float* __restrict__ bgd,
                        const float* __restrict__ rnorm, float* __restrict__ s0) {
    int b = blockIdx.z, pt = blockIdx.y, qt = blockIdx.x;
    int hb0 = pt * 2, yf0 = qt * 2;
    __shared__ float bgS[CK][4][36];
    __shared__ float fgS[CK][4][36];
    int t = threadIdx.x;
    int tp = t >> 4, tq = t & 15;
    float acc[4][4] = {};
    const float* bgB = bgd + b * NC * 1024;
    const float* fgB = fgd + b * NC * 1024;
    for (int c0 = 0; c0 < NC; c0 += CK) {
        __syncthreads();
        for (int idx = t; idx < CK * 4 * 36; idx += 256) {
            int cc = idx / 144, rem = idx % 144, r = rem / 36, col = rem % 36;
            int hb = hb0 - 1 + r, wb = col - 1;
            float bv = 0.f, fv = 0.f;
            if (hb >= 0 && hb < 32 && wb >= 0 && wb < 32)
                bv = bgB[(c0 + cc) * 1024 + hb * 32 + wb];
            int yf = yf0 - 1 + r, xf = col - 1;
            if (yf >= 0 && yf < 32 && xf >= 0 && xf < 32)
                fv = fgB[(c0 + cc) * 1024 + yf * 32 + xf];
            bgS[cc][r][col] = bv;
            fgS[cc][r][col] = fv;
        }
        __syncthreads();
        int hbl = tp >> 3, wb0 = (tp & 7) * 4;
        int yfl = tq >> 3, xf0 = (tq & 7) * 4;
        for (int cc = 0; cc < CK; ++cc) {
            float bgr[3][6], fgr[3][6];
#pragma unroll
            for (int r = 0; r < 3; ++r)
#pragma unroll
                for (int k = 0; k < 6; ++k) {
                    bgr[r][k] = bgS[cc][hbl + r][wb0 + k];
                    fgr[r][k] = fgS[cc][yfl + r][xf0 + k];
                }
#pragma unroll
            for (int di = 0; di < 3; ++di)
#pragma unroll
                for (int dj = 0; dj < 3; ++dj)
#pragma unroll
                    for (int i = 0; i < 4; ++i)
#pragma unroll
                        for (int j = 0; j < 4; ++j)
                            acc[i][j] += bgr[di][i + dj] * fgr[di][j + dj];
        }
    }
    // write
#pragma unroll
    for (int i = 0; i < 4; ++i) {
        int P = pt * 64 + tp * 4 + i;
        float rn = rnorm[b * 1024 + P];
        int Q0 = qt * 64 + tq * 4;
        float4 v;
        v.x = acc[i][0] * rn; v.y = acc[i][1] * rn;
        v.z = acc[i][2] * rn; v.w = acc[i][3] * rn;
        *(float4*)&s0[((unsigned)(b * 1024 + P) << 10) + Q0] = v;
    }
}

__device__ __forceinline__ int untr(int v) { return (v & 31) * 32 + (v >> 5); }

// s2[b][R][T] = sum_{k} sum_{j} s0[b][untr(R+k)+j][untr(T+k)+j]  (only eq rows)
__global__ void k_fuse(const float* __restrict__ s0, float* __restrict__ s2,
                       const int* __restrict__ eq) {
    int R = blockIdx.y;
    if (!eq[R]) return;
    int b = blockIdx.z;
    int T = blockIdx.x * 256 + threadIdx.x;
    const float* S = s0 + (unsigned)b * 1048576u;
    float acc = 0.f;
#pragma unroll
    for (int k = -1; k <= 1; ++k) {
        int Rk = R + k, Tk = T + k;
        if (Rk < 0 || Rk >= 1024 || Tk < 0 || Tk >= 1024) continue;
        int Pr = untr(Rk), Qc = untr(Tk);
#pragma unroll
        for (int j = -1; j <= 1; ++j) {
            int r = Pr + j, cI = Qc + j;
            if (r < 0 || r >= 1024 || cI < 0 || cI >= 1024) continue;
            acc += S[(unsigned)r * 1024u + cI];
        }
    }
    s2[(unsigned)b * 1048576u + (unsigned)R * 1024u + T] = acc;
}

// pass 1: per (b,T) compute max and denominator (masked rows contribute exp(0)=1)
__global__ void k_soft1(const float* __restrict__ s2, const int* __restrict__ eq,
                        float* __restrict__ M, float* __restrict__ den) {
    int b = blockIdx.y;
    int T = blockIdx.x * 256 + threadIdx.x;
    const float* S = s2 + (unsigned)b * 1048576u;
    float m = -3e38f;
    int cnt0 = 0;
    for (int R = 0; R < 1024; ++R) {
        if (eq[R]) m = fmaxf(m, S[(unsigned)R * 1024u + T]);
        else ++cnt0;
    }
    if (cnt0 > 0) m = fmaxf(m, 0.f);
    float d = (float)cnt0 * expf(-10.f * m);
    for (int R = 0; R < 1024; ++R)
        if (eq[R]) d += expf(10.f * (S[(unsigned)R * 1024u + T] - m));
    M[b * 1024 + T] = m;
    den[b * 1024 + T] = d;
}

// wgt = exp(10*(s2-M))/den  in place (eq rows only)
__global__ void k_wgt(float* __restrict__ s2, const int* __restrict__ eq,
                      const float* __restrict__ M, const float* __restrict__ den) {
    int R = blockIdx.y;
    if (!eq[R]) return;
    int b = blockIdx.z;
    int T = blockIdx.x * 256 + threadIdx.x;
    unsigned o = (unsigned)b * 1048576u + (unsigned)R * 1024u + T;
    float v = s2[o];
    s2[o] = expf(10.f * (v - M[b * 1024 + T])) / den[b * 1024 + T];
}

// y[b,c,oy,ox] = 0.25 * sum_{R in S} sum_{(p,a),(q,bb)} wgt[b,R,p*32+q]*BG[b, 2hb-1+a, 2wb-1+bb, c]
__global__ void k_deconv(const float* __restrict__ wgt, const float* __restrict__ BGt,
                         const int* __restrict__ eq, float* __restrict__ y) {
    int b = blockIdx.y, oy = blockIdx.x;
    int t = threadIdx.x;
    int ox = t & 63, cg = t >> 6; // cg: 0..3 -> c block of 32
    __shared__ float bgS[8][128];  // [pp*4+bb][c]
    __shared__ float wgtS[2][32];  // [pp][q]
    int a_lo = (oy + 1) & 1;
    int p_lo = (oy + 1 - a_lo) >> 1;
    int b_lo = (ox + 1) & 1;
    int q_lo = (ox + 1 - b_lo) >> 1;
    float acc[32];
#pragma unroll
    for (int k = 0; k < 32; ++k) acc[k] = 0.f;
    for (int R = 0; R < 1024; ++R) {
        if (!eq[R]) continue;
        __syncthreads();
        if (t < 64) {
            int pp = t >> 5, q = t & 31;
            int p = p_lo - pp;
            float wv = 0.f;
            if (p >= 0 && p < 32)
                wv = wgt[(unsigned)(b * 1024 + R) * 1024u + p * 32 + q];
            wgtS[pp][q] = wv;
        }
        {
            int pos = t >> 5, c4 = (t & 31) << 2;
            int pp = pos >> 2, bb = pos & 3;
            int hb = R >> 5, wb = R & 31;
            int row = 2 * hb - 1 + a_lo + 2 * pp;
            int col = 2 * wb - 1 + bb;
            float4 v = make_float4(0.f, 0.f, 0.f, 0.f);
            if (row >= 0 && row < 64 && col >= 0 && col < 64)
                v = *(const float4*)&BGt[(unsigned)((b * 64 + row) * 64 + col) * 128u + c4];
            *(float4*)&bgS[pos][c4] = v;
        }
        __syncthreads();
#pragma unroll
        for (int pp = 0; pp < 2; ++pp) {
#pragma unroll
            for (int qq = 0; qq < 2; ++qq) {
                int q = q_lo - qq;
                if (q < 0 || q >= 32) continue;
                float w = wgtS[pp][q];
                int bb = b_lo + 2 * qq;
                const float* bp = &bgS[pp * 4 + bb][cg * 32];
#pragma unroll
                for (int k = 0; k < 32; ++k) acc[k] += w * bp[k];
            }
        }
    }
    float* Y = y + (unsigned)((b * NC + cg * 32) * 64 + oy) * 64u + ox;
#pragma unroll
    for (int k = 0; k < 32; ++k) Y[(unsigned)k * 4096u] = acc[k] * 0.25f;
}

extern "C" void kernel_launch(void* const* d_in, const int* in_sizes, int n_in,
                              void* d_out, int out_size, void* d_ws, size_t ws_size,
                              hipStream_t stream) {
    const float* fg   = (const float*)d_in[0];
    const float* bg   = (const float*)d_in[1];
    const float* mask = (const float*)d_in[2];
    float* y  = (float*)d_out;
    float* ws = (float*)d_ws;

    float* fgd   = ws + OFF_FGD;
    float* bgd   = ws + OFF_BGD;
    float* BGt   = ws + OFF_BGT;
    float* SS    = ws + OFF_SS;
    float* rnorm = ws + OFF_RNORM;
    float* Mb    = ws + OFF_M;
    float* den   = ws + OFF_DEN;
    int*   eq    = (int*)(ws + OFF_EQ);
    float* s0    = ws + OFF_S0;
    float* s2    = ws + OFF_S2;

    k_down<<<4096, 256, 0, stream>>>(fg, bg, fgd, bgd);
    k_tr<<<dim3(64, 8), 256, 0, stream>>>(bg, BGt);
    k_ss<<<32, 256, 0, stream>>>(bgd, SS);
    k_eq<<<4, 256, 0, stream>>>(mask, eq);
    k_norm<<<32, 256, 0, stream>>>(SS, rnorm);
    k_score<<<dim3(16, 16, 8), 256, 0, stream>>>(fgd, bgd, rnorm, s0);
    k_fuse<<<dim3(4, 1024, 8), 256, 0, stream>>>(s0, s2, eq);
    k_soft1<<<dim3(4, 8), 256, 0, stream>>>(s2, eq, Mb, den);
    k_wgt<<<dim3(4, 1024, 8), 256, 0, stream>>>(s2, eq, Mb, den);
    k_deconv<<<dim3(64, 8), 256, 0, stream>>>(s2, BGt, eq, y);
}

// Round 2
// 248.980 us; speedup vs baseline: 2.7201x; 2.7201x over previous
//
#include <hip/hip_runtime.h>

typedef _Float16 half8 __attribute__((ext_vector_type(8)));
typedef float f32x4 __attribute__((ext_vector_type(4)));
typedef unsigned short us8 __attribute__((ext_vector_type(8)));
typedef unsigned short ush;
typedef unsigned int uint32;

#define PIMG (34*34*128)   // halfs per padded per-batch image

// workspace byte offsets
#define OFF_FGH  0ull
#define OFF_FGL  2367488ull
#define OFF_BGH  4734976ull
#define OFF_BGL  7102464ull
#define OFF_BGT  9469952ull
#define OFF_SS   17858560ull
#define OFF_RN   17891328ull
#define OFF_MM   17924096ull
#define OFF_DEN  17956864ull
#define OFF_LIST 17989632ull
#define OFF_NACT 17993728ull
#define OFF_S0   17997824ull
#define OFF_S2   51552256ull
// end 85,106,688 bytes

static __device__ __forceinline__ ush f2h(float f) {
    union { _Float16 h; ush u; } c; c.h = (_Float16)f; return c.u;
}
static __device__ __forceinline__ float h2f(ush u) {
    union { _Float16 h; ush u; } c; c.u = u; return (float)c.h;
}

// fg/bg fp32 [b][c][64][64] -> downsampled padded f16 hi/lo [b][34][34][128]
__global__ void k_prep(const float* __restrict__ fg, const float* __restrict__ bg,
                       ush* __restrict__ fgh, ush* __restrict__ fgl,
                       ush* __restrict__ bgh, ush* __restrict__ bgl) {
    int y = blockIdx.x, b = blockIdx.y, t = threadIdx.x;
    int xq = t & 31, cg = t >> 5;
    __shared__ ush lfh[32][130], lfl[32][130], lbh[32][130], lbl[32][130];
    for (int c0 = 0; c0 < 128; c0 += 8) {
        int c = c0 + cg;
        int src = ((b * 128 + c) * 64 + 2 * y) * 64 + 2 * xq;
        float vf = fg[src], vb = bg[src];
        _Float16 fh = (_Float16)vf; float fr = vf - (float)fh;
        _Float16 bh = (_Float16)vb; float br = vb - (float)bh;
        union { _Float16 h; ush u; } c1, c2, c3, c4;
        c1.h = fh; c2.h = (_Float16)fr; c3.h = bh; c4.h = (_Float16)br;
        lfh[xq][c] = c1.u; lfl[xq][c] = c2.u; lbh[xq][c] = c3.u; lbl[xq][c] = c4.u;
    }
    __syncthreads();
    unsigned base = ((b * 34 + y + 1) * 34 + 1) * 128;  // half index
    for (int k = t; k < 2048; k += 256) {               // uint index
        int x = k >> 6, cp = (k & 63) * 2;
        ((uint32*)(fgh + base))[k] = *(const uint32*)&lfh[x][cp];
        ((uint32*)(fgl + base))[k] = *(const uint32*)&lfl[x][cp];
        ((uint32*)(bgh + base))[k] = *(const uint32*)&lbh[x][cp];
        ((uint32*)(bgl + base))[k] = *(const uint32*)&lbl[x][cp];
    }
}

// BGt[b][y][x][c] (f16) = background[b][c][y][x], full resolution
__global__ void k_tr(const float* __restrict__ bg, ush* __restrict__ BGt) {
    int b = blockIdx.y, y = blockIdx.x, t = threadIdx.x;
    __shared__ float lds[64 * 129];
    int xx = t & 63;
    for (int c0 = 0; c0 < 128; c0 += 4) {
        int c = c0 + (t >> 6);
        lds[xx * 129 + c] = bg[((b * 128 + c) * 64 + y) * 64 + xx];
    }
    __syncthreads();
    uint32* dst = (uint32*)(BGt + (size_t)(b * 64 + y) * 8192);
    for (int j = t; j < 4096; j += 256) {
        int x = j >> 6, cp = (j & 63) * 2;
        uint32 h0 = f2h(lds[x * 129 + cp]);
        uint32 h1 = f2h(lds[x * 129 + cp + 1]);
        dst[j] = h0 | (h1 << 16);
    }
}

// eq flags + deterministic compaction (single block, 1024 threads)
__global__ void k_eqscan(const float* __restrict__ mask, int* __restrict__ L,
                         int* __restrict__ nact) {
    __shared__ int f[1024], sc[1024];
    int l = threadIdx.x;
    int hm = l >> 5, wm = l & 31;
    int any = 0;
    for (int di = -1; di <= 1; ++di)
        for (int dj = -1; dj <= 1; ++dj) {
            int yy = hm + di, xx = wm + dj;
            if (yy >= 0 && yy < 32 && xx >= 0 && xx < 32)
                any |= (mask[(2 * yy) * 64 + 2 * xx] != 0.0f);
        }
    f[l] = !any; sc[l] = f[l];
    __syncthreads();
    for (int off = 1; off < 1024; off <<= 1) {
        int v = (l >= off) ? sc[l - off] : 0;
        __syncthreads();
        sc[l] += v;
        __syncthreads();
    }
    if (f[l]) L[sc[l] - 1] = l;
    if (l == 1023) nact[0] = sc[1023];
}

// SS[b][yx] = sum_c (hi+lo)^2 of downsampled bg
__global__ void k_ss(const ush* __restrict__ bgh, const ush* __restrict__ bgl,
                     float* __restrict__ SS) {
    int i = blockIdx.x * 256 + threadIdx.x; // 8192
    int b = i >> 10, yx = i & 1023, yy = yx >> 5, xx = yx & 31;
    size_t base = ((size_t)(b * 34 + yy + 1) * 34 + xx + 1) * 128;
    float s = 0.f;
    for (int c = 0; c < 128; c += 8) {
        us8 vh = *(const us8*)(bgh + base + c);
        us8 vl = *(const us8*)(bgl + base + c);
#pragma unroll
        for (int j = 0; j < 8; ++j) {
            float v = h2f(vh[j]) + h2f(vl[j]);
            s += v * v;
        }
    }
    SS[i] = s;
}

__global__ void k_norm(const float* __restrict__ SS, float* __restrict__ rnorm) {
    int i = blockIdx.x * 256 + threadIdx.x; // 8192
    int b = i >> 10, P = i & 1023, hb = P >> 5, wb = P & 31;
    float n2 = 0.f;
    for (int di = -1; di <= 1; ++di)
        for (int dj = -1; dj <= 1; ++dj) {
            int yy = hb + di, xx = wb + dj;
            if (yy >= 0 && yy < 32 && xx >= 0 && xx < 32)
                n2 += SS[b * 1024 + yy * 32 + xx];
        }
    rnorm[i] = 1.0f / fmaxf(sqrtf(n2), 1e-4f);
}

// MFMA score: s0[b][P][Q] = rnorm[P] * sum_{o,c} bg(P,o,c)*fg(Q,o,c), fp16 hi/lo 3-pass
__global__ __launch_bounds__(256, 2)
void k_smfma(const ush* __restrict__ fgh, const ush* __restrict__ fgl,
             const ush* __restrict__ bgh, const ush* __restrict__ bgl,
             const float* __restrict__ rnorm, float* __restrict__ s0) {
    int qt = blockIdx.x, pt = blockIdx.y, b = blockIdx.z;
    int t = threadIdx.x, wid = t >> 6, lane = t & 63;
    int wp = wid >> 1, wq = wid & 1;
    __shared__ ulong2 smem_raw[4096];   // 64 KB: B_hi | B_lo | A_hi | A_lo (16 KB each)
    char* smem = (char*)smem_raw;

    const ush* src = (wid == 0 ? bgh : wid == 1 ? bgl : wid == 2 ? fgh : fgl)
                     + (size_t)b * PIMG;
    int tb = (wid < 2 ? pt : qt) * 4;
    // per-lane staging addend: x-step + pre-swizzled c-group (involution slot^row&7)
    unsigned laneAdd = ((unsigned)(lane >> 3) << 8)
                     + ((unsigned)((lane & 7) ^ ((lane >> 3) & 7)) << 4);

    f32x4 acc[4][4];
#pragma unroll
    for (int i = 0; i < 4; ++i)
#pragma unroll
        for (int j = 0; j < 4; ++j) acc[i][j] = (f32x4){0.f, 0.f, 0.f, 0.f};

    for (int o = 0; o < 9; ++o) {
        int dy = o / 3 - 1, dx = o % 3 - 1;
        for (int ch = 0; ch < 2; ++ch) {
            __syncthreads();
            // stage: each wave fills its 128x64-half tile (16 x 8-row wave loads)
            for (int i = 0; i < 16; ++i) {
                int r0 = i * 8;
                int yimg = tb + (r0 >> 5) + dy + 1;
                int x0 = (r0 & 31) + dx + 1;
                const char* gp = (const char*)src + ((unsigned)(yimg * 34 + x0) << 8)
                               + ((unsigned)ch << 7) + laneAdd;
                char* lp = smem + (wid << 14) + (r0 << 7);
                __builtin_amdgcn_global_load_lds(
                    (const __attribute__((address_space(1))) void*)gp,
                    (__attribute__((address_space(3))) void*)lp, 16, 0, 0);
            }
            __syncthreads();
            // compute: 2 k-halves x 16 frag-pairs x 3 passes
#pragma unroll
            for (int kh = 0; kh < 2; ++kh) {
                int g = (lane >> 4) + kh * 4;
                half8 bh8[4], bl8[4], ah8[4], al8[4];
#pragma unroll
                for (int i = 0; i < 4; ++i) {
                    int prow = wp * 64 + i * 16 + (lane & 15);
                    unsigned offb = ((unsigned)prow << 7) + ((unsigned)(g ^ (prow & 7)) << 4);
                    bh8[i] = *(const half8*)(smem + offb);
                    bl8[i] = *(const half8*)(smem + 16384 + offb);
                    int qrow = wq * 64 + i * 16 + (lane & 15);
                    unsigned offa = ((unsigned)qrow << 7) + ((unsigned)(g ^ (qrow & 7)) << 4);
                    ah8[i] = *(const half8*)(smem + 32768 + offa);
                    al8[i] = *(const half8*)(smem + 49152 + offa);
                }
#pragma unroll
                for (int i = 0; i < 4; ++i)
#pragma unroll
                    for (int j = 0; j < 4; ++j) {
                        acc[i][j] = __builtin_amdgcn_mfma_f32_16x16x32_f16(bh8[i], ah8[j], acc[i][j], 0, 0, 0);
                        acc[i][j] = __builtin_amdgcn_mfma_f32_16x16x32_f16(bh8[i], al8[j], acc[i][j], 0, 0, 0);
                        acc[i][j] = __builtin_amdgcn_mfma_f32_16x16x32_f16(bl8[i], ah8[j], acc[i][j], 0, 0, 0);
                    }
            }
        }
    }
    // epilogue: C row=(lane>>4)*4+reg <-> P (bg), col=lane&15 <-> Q (fg)
    int col = lane & 15, rgrp = (lane >> 4) << 2;
#pragma unroll
    for (int i = 0; i < 4; ++i) {
        int Pb = pt * 128 + wp * 64 + i * 16 + rgrp;
        float rn0 = rnorm[b * 1024 + Pb + 0];
        float rn1 = rnorm[b * 1024 + Pb + 1];
        float rn2 = rnorm[b * 1024 + Pb + 2];
        float rn3 = rnorm[b * 1024 + Pb + 3];
#pragma unroll
        for (int j = 0; j < 4; ++j) {
            int Q = qt * 128 + wq * 64 + j * 16 + col;
            float* dst = s0 + ((size_t)(b * 1024 + Pb) << 10) + Q;
            dst[0]    = acc[i][j][0] * rn0;
            dst[1024] = acc[i][j][1] * rn1;
            dst[2048] = acc[i][j][2] * rn2;
            dst[3072] = acc[i][j][3] * rn3;
        }
    }
}

__device__ __forceinline__ int untr(int v) { return (v & 31) * 32 + (v >> 5); }

// s2[b][R][T] for active R only (double diagonal fuse + flat transpose)
__global__ void k_fuse(const float* __restrict__ s0, float* __restrict__ s2,
                       const int* __restrict__ L, const int* __restrict__ nactp) {
    int nact = *nactp;
    int b = blockIdx.z;
    int T = blockIdx.x * 256 + threadIdx.x;
    const float* S = s0 + (size_t)b * 1048576;
    for (int ai = blockIdx.y; ai < nact; ai += 32) {
        int R = L[ai];
        float acc = 0.f;
#pragma unroll
        for (int k = -1; k <= 1; ++k) {
            int Rk = R + k, Tk = T + k;
            if (Rk < 0 || Rk >= 1024 || Tk < 0 || Tk >= 1024) continue;
            int Pr = untr(Rk), Qc = untr(Tk);
#pragma unroll
            for (int j = -1; j <= 1; ++j) {
                int r = Pr + j, cI = Qc + j;
                if (r < 0 || r >= 1024 || cI < 0 || cI >= 1024) continue;
                acc += S[(size_t)r * 1024 + cI];
            }
        }
        s2[(size_t)b * 1048576 + (size_t)R * 1024 + T] = acc;
    }
}

__global__ void k_soft1(const float* __restrict__ s2, const int* __restrict__ L,
                        const int* __restrict__ nactp, float* __restrict__ M,
                        float* __restrict__ den) {
    int nact = *nactp;
    int b = blockIdx.y;
    int T = blockIdx.x * 256 + threadIdx.x;
    const float* S = s2 + (size_t)b * 1048576;
    float m = -3e38f;
    for (int ai = 0; ai < nact; ++ai) m = fmaxf(m, S[(size_t)L[ai] * 1024 + T]);
    int cnt0 = 1024 - nact;
    if (cnt0 > 0) m = fmaxf(m, 0.f);
    float d = (float)cnt0 * expf(-10.f * m);
    for (int ai = 0; ai < nact; ++ai) d += expf(10.f * (S[(size_t)L[ai] * 1024 + T] - m));
    M[b * 1024 + T] = m;
    den[b * 1024 + T] = d;
}

__global__ void k_wgt(float* __restrict__ s2, const int* __restrict__ L,
                      const int* __restrict__ nactp, const float* __restrict__ M,
                      const float* __restrict__ den) {
    int nact = *nactp;
    int b = blockIdx.z;
    int T = blockIdx.x * 256 + threadIdx.x;
    for (int ai = blockIdx.y; ai < nact; ai += 32) {
        int R = L[ai];
        size_t o = (size_t)b * 1048576 + (size_t)R * 1024 + T;
        float v = s2[o];
        s2[o] = expf(10.f * (v - M[b * 1024 + T])) / den[b * 1024 + T];
    }
}

__global__ void k_deconv(const float* __restrict__ wgt, const ush* __restrict__ BGt,
                         const int* __restrict__ L, const int* __restrict__ nactp,
                         float* __restrict__ y) {
    int nact = *nactp;
    int b = blockIdx.y, oy = blockIdx.x, t = threadIdx.x;
    int ox = t & 63, cg = t >> 6;
    __shared__ float bgS[8][128];
    __shared__ float wgtS[2][32];
    int a_lo = (oy + 1) & 1, p_lo = (oy + 1 - a_lo) >> 1;
    int b_lo = (ox + 1) & 1, q_lo = (ox + 1 - b_lo) >> 1;
    float acc[32];
#pragma unroll
    for (int k = 0; k < 32; ++k) acc[k] = 0.f;
    for (int ai = 0; ai < nact; ++ai) {
        int R = L[ai];
        __syncthreads();
        if (t < 64) {
            int pp = t >> 5, q = t & 31;
            int p = p_lo - pp;
            float wv = 0.f;
            if (p >= 0 && p < 32)
                wv = wgt[(size_t)(b * 1024 + R) * 1024 + p * 32 + q];
            wgtS[pp][q] = wv;
        }
        {
            int pos = t >> 5, c4 = (t & 31) << 2;
            int pp = pos >> 2, bb = pos & 3;
            int hb = R >> 5, wb = R & 31;
            int row = 2 * hb - 1 + a_lo + 2 * pp;
            int col = 2 * wb - 1 + bb;
            float4 v = make_float4(0.f, 0.f, 0.f, 0.f);
            if (row >= 0 && row < 64 && col >= 0 && col < 64) {
                const ush* p4 = BGt + ((size_t)((b * 64 + row) * 64 + col) << 7) + c4;
                uint2 u = *(const uint2*)p4;
                v.x = h2f((ush)(u.x & 0xffff)); v.y = h2f((ush)(u.x >> 16));
                v.z = h2f((ush)(u.y & 0xffff)); v.w = h2f((ush)(u.y >> 16));
            }
            *(float4*)&bgS[pos][c4] = v;
        }
        __syncthreads();
#pragma unroll
        for (int pp = 0; pp < 2; ++pp)
#pragma unroll
            for (int qq = 0; qq < 2; ++qq) {
                int q = q_lo - qq;
                if (q < 0 || q >= 32) continue;
                float w = wgtS[pp][q];
                int bb = b_lo + 2 * qq;
                const float* bp = &bgS[pp * 4 + bb][cg * 32];
#pragma unroll
                for (int k = 0; k < 32; ++k) acc[k] += w * bp[k];
            }
    }
    float* Y = y + (size_t)((b * 128 + cg * 32) * 64 + oy) * 64 + ox;
#pragma unroll
    for (int k = 0; k < 32; ++k) Y[(size_t)k * 4096] = acc[k] * 0.25f;
}

extern "C" void kernel_launch(void* const* d_in, const int* in_sizes, int n_in,
                              void* d_out, int out_size, void* d_ws, size_t ws_size,
                              hipStream_t stream) {
    (void)in_sizes; (void)n_in; (void)out_size; (void)ws_size;
    const float* fg   = (const float*)d_in[0];
    const float* bg   = (const float*)d_in[1];
    const float* mask = (const float*)d_in[2];
    float* y = (float*)d_out;
    char* ws = (char*)d_ws;

    ush*   fgh   = (ush*)(ws + OFF_FGH);
    ush*   fgl   = (ush*)(ws + OFF_FGL);
    ush*   bgh   = (ush*)(ws + OFF_BGH);
    ush*   bgl   = (ush*)(ws + OFF_BGL);
    ush*   BGt   = (ush*)(ws + OFF_BGT);
    float* SS    = (float*)(ws + OFF_SS);
    float* rnorm = (float*)(ws + OFF_RN);
    float* Mb    = (float*)(ws + OFF_MM);
    float* den   = (float*)(ws + OFF_DEN);
    int*   Lst   = (int*)(ws + OFF_LIST);
    int*   nact  = (int*)(ws + OFF_NACT);
    float* s0    = (float*)(ws + OFF_S0);
    float* s2    = (float*)(ws + OFF_S2);

    hipMemsetAsync(ws, 0, OFF_BGT, stream);  // zero padded-image borders
    k_prep<<<dim3(32, 8), 256, 0, stream>>>(fg, bg, fgh, fgl, bgh, bgl);
    k_tr<<<dim3(64, 8), 256, 0, stream>>>(bg, BGt);
    k_eqscan<<<1, 1024, 0, stream>>>(mask, Lst, nact);
    k_ss<<<32, 256, 0, stream>>>(bgh, bgl, SS);
    k_norm<<<32, 256, 0, stream>>>(SS, rnorm);
    k_smfma<<<dim3(8, 8, 8), 256, 0, stream>>>(fgh, fgl, bgh, bgl, rnorm, s0);
    k_fuse<<<dim3(4, 32, 8), 256, 0, stream>>>(s0, s2, Lst, nact);
    k_soft1<<<dim3(4, 8), 256, 0, stream>>>(s2, Lst, nact, Mb, den);
    k_wgt<<<dim3(4, 32, 8), 256, 0, stream>>>(s2, Lst, nact, Mb, den);
    k_deconv<<<dim3(64, 8), 256, 0, stream>>>(s2, BGt, Lst, nact, y);
}

// Round 3
// 197.331 us; speedup vs baseline: 3.4321x; 1.2617x over previous
//
#include <hip/hip_runtime.h>

typedef _Float16 half8 __attribute__((ext_vector_type(8)));
typedef float f32x4 __attribute__((ext_vector_type(4)));
typedef unsigned short us8 __attribute__((ext_vector_type(8)));
typedef unsigned short ush;
typedef unsigned int uint32;

#define PIMG (34*34*128)   // halfs per padded per-batch image

// workspace byte offsets
#define OFF_FGH  0ull
#define OFF_FGL  2367488ull
#define OFF_BGH  4734976ull
#define OFF_BGL  7102464ull
#define OFF_BGT  9469952ull
#define OFF_SS   17858560ull
#define OFF_RN   17891328ull
#define OFF_MM   17924096ull
#define OFF_DEN  17956864ull
#define OFF_LIST 17989632ull
#define OFF_NACT 17993728ull
#define OFF_S0   17997824ull   // 32 MB: s0 scores, later reused as CT
#define OFF_S2   51552256ull
// end 85,106,688 bytes

static __device__ __forceinline__ ush f2h(float f) {
    union { _Float16 h; ush u; } c; c.h = (_Float16)f; return c.u;
}
static __device__ __forceinline__ float h2f(ush u) {
    union { _Float16 h; ush u; } c; c.u = u; return (float)c.h;
}

// fg/bg fp32 [b][c][64][64] -> downsampled padded f16 hi/lo [b][34][34][128]
__global__ void k_prep(const float* __restrict__ fg, const float* __restrict__ bg,
                       ush* __restrict__ fgh, ush* __restrict__ fgl,
                       ush* __restrict__ bgh, ush* __restrict__ bgl) {
    int y = blockIdx.x, b = blockIdx.y, t = threadIdx.x;
    int xq = t & 31, cg = t >> 5;
    __shared__ ush lfh[32][130], lfl[32][130], lbh[32][130], lbl[32][130];
    for (int c0 = 0; c0 < 128; c0 += 8) {
        int c = c0 + cg;
        int src = ((b * 128 + c) * 64 + 2 * y) * 64 + 2 * xq;
        float vf = fg[src], vb = bg[src];
        _Float16 fh = (_Float16)vf; float fr = vf - (float)fh;
        _Float16 bh = (_Float16)vb; float br = vb - (float)bh;
        union { _Float16 h; ush u; } c1, c2, c3, c4;
        c1.h = fh; c2.h = (_Float16)fr; c3.h = bh; c4.h = (_Float16)br;
        lfh[xq][c] = c1.u; lfl[xq][c] = c2.u; lbh[xq][c] = c3.u; lbl[xq][c] = c4.u;
    }
    __syncthreads();
    unsigned base = ((b * 34 + y + 1) * 34 + 1) * 128;  // half index
    for (int k = t; k < 2048; k += 256) {               // uint index
        int x = k >> 6, cp = (k & 63) * 2;
        ((uint32*)(fgh + base))[k] = *(const uint32*)&lfh[x][cp];
        ((uint32*)(fgl + base))[k] = *(const uint32*)&lfl[x][cp];
        ((uint32*)(bgh + base))[k] = *(const uint32*)&lbh[x][cp];
        ((uint32*)(bgl + base))[k] = *(const uint32*)&lbl[x][cp];
    }
}

// BGt[b][y][x][c] (f16) = background[b][c][y][x], full resolution
__global__ void k_tr(const float* __restrict__ bg, ush* __restrict__ BGt) {
    int b = blockIdx.y, y = blockIdx.x, t = threadIdx.x;
    __shared__ float lds[64 * 129];
    int xx = t & 63;
    for (int c0 = 0; c0 < 128; c0 += 4) {
        int c = c0 + (t >> 6);
        lds[xx * 129 + c] = bg[((b * 128 + c) * 64 + y) * 64 + xx];
    }
    __syncthreads();
    uint32* dst = (uint32*)(BGt + (size_t)(b * 64 + y) * 8192);
    for (int j = t; j < 4096; j += 256) {
        int x = j >> 6, cp = (j & 63) * 2;
        uint32 h0 = f2h(lds[x * 129 + cp]);
        uint32 h1 = f2h(lds[x * 129 + cp + 1]);
        dst[j] = h0 | (h1 << 16);
    }
}

// eq flags + deterministic compaction (single block, 1024 threads)
__global__ void k_eqscan(const float* __restrict__ mask, int* __restrict__ L,
                         int* __restrict__ nact) {
    __shared__ int f[1024], sc[1024];
    int l = threadIdx.x;
    int hm = l >> 5, wm = l & 31;
    int any = 0;
    for (int di = -1; di <= 1; ++di)
        for (int dj = -1; dj <= 1; ++dj) {
            int yy = hm + di, xx = wm + dj;
            if (yy >= 0 && yy < 32 && xx >= 0 && xx < 32)
                any |= (mask[(2 * yy) * 64 + 2 * xx] != 0.0f);
        }
    f[l] = !any; sc[l] = f[l];
    __syncthreads();
    for (int off = 1; off < 1024; off <<= 1) {
        int v = (l >= off) ? sc[l - off] : 0;
        __syncthreads();
        sc[l] += v;
        __syncthreads();
    }
    if (f[l]) L[sc[l] - 1] = l;
    if (l == 1023) nact[0] = sc[1023];
}

// SS[b][yx] = sum_c (hi+lo)^2 of downsampled bg
__global__ void k_ss(const ush* __restrict__ bgh, const ush* __restrict__ bgl,
                     float* __restrict__ SS) {
    int i = blockIdx.x * 256 + threadIdx.x; // 8192
    int b = i >> 10, yx = i & 1023, yy = yx >> 5, xx = yx & 31;
    size_t base = ((size_t)(b * 34 + yy + 1) * 34 + xx + 1) * 128;
    float s = 0.f;
    for (int c = 0; c < 128; c += 8) {
        us8 vh = *(const us8*)(bgh + base + c);
        us8 vl = *(const us8*)(bgl + base + c);
#pragma unroll
        for (int j = 0; j < 8; ++j) {
            float v = h2f(vh[j]) + h2f(vl[j]);
            s += v * v;
        }
    }
    SS[i] = s;
}

__global__ void k_norm(const float* __restrict__ SS, float* __restrict__ rnorm) {
    int i = blockIdx.x * 256 + threadIdx.x; // 8192
    int b = i >> 10, P = i & 1023, hb = P >> 5, wb = P & 31;
    float n2 = 0.f;
    for (int di = -1; di <= 1; ++di)
        for (int dj = -1; dj <= 1; ++dj) {
            int yy = hb + di, xx = wb + dj;
            if (yy >= 0 && yy < 32 && xx >= 0 && xx < 32)
                n2 += SS[b * 1024 + yy * 32 + xx];
        }
    rnorm[i] = 1.0f / fmaxf(sqrtf(n2), 1e-4f);
}

// MFMA score: s0[b][P][Q] = rnorm[P] * sum_{o,c} bg(P,o,c)*fg(Q,o,c), fp16 hi/lo 3-pass
__global__ __launch_bounds__(256, 2)
void k_smfma(const ush* __restrict__ fgh, const ush* __restrict__ fgl,
             const ush* __restrict__ bgh, const ush* __restrict__ bgl,
             const float* __restrict__ rnorm, float* __restrict__ s0) {
    int qt = blockIdx.x, pt = blockIdx.y, b = blockIdx.z;
    int t = threadIdx.x, wid = t >> 6, lane = t & 63;
    int wp = wid >> 1, wq = wid & 1;
    __shared__ ulong2 smem_raw[4096];   // 64 KB: B_hi | B_lo | A_hi | A_lo (16 KB each)
    char* smem = (char*)smem_raw;

    const ush* src = (wid == 0 ? bgh : wid == 1 ? bgl : wid == 2 ? fgh : fgl)
                     + (size_t)b * PIMG;
    int tb = (wid < 2 ? pt : qt) * 4;
    unsigned laneAdd = ((unsigned)(lane >> 3) << 8)
                     + ((unsigned)((lane & 7) ^ ((lane >> 3) & 7)) << 4);

    f32x4 acc[4][4];
#pragma unroll
    for (int i = 0; i < 4; ++i)
#pragma unroll
        for (int j = 0; j < 4; ++j) acc[i][j] = (f32x4){0.f, 0.f, 0.f, 0.f};

    for (int o = 0; o < 9; ++o) {
        int dy = o / 3 - 1, dx = o % 3 - 1;
        for (int ch = 0; ch < 2; ++ch) {
            __syncthreads();
            for (int i = 0; i < 16; ++i) {
                int r0 = i * 8;
                int yimg = tb + (r0 >> 5) + dy + 1;
                int x0 = (r0 & 31) + dx + 1;
                const char* gp = (const char*)src + ((unsigned)(yimg * 34 + x0) << 8)
                               + ((unsigned)ch << 7) + laneAdd;
                char* lp = smem + (wid << 14) + (r0 << 7);
                __builtin_amdgcn_global_load_lds(
                    (const __attribute__((address_space(1))) void*)gp,
                    (__attribute__((address_space(3))) void*)lp, 16, 0, 0);
            }
            __syncthreads();
#pragma unroll
            for (int kh = 0; kh < 2; ++kh) {
                int g = (lane >> 4) + kh * 4;
                half8 bh8[4], bl8[4], ah8[4], al8[4];
#pragma unroll
                for (int i = 0; i < 4; ++i) {
                    int prow = wp * 64 + i * 16 + (lane & 15);
                    unsigned offb = ((unsigned)prow << 7) + ((unsigned)(g ^ (prow & 7)) << 4);
                    bh8[i] = *(const half8*)(smem + offb);
                    bl8[i] = *(const half8*)(smem + 16384 + offb);
                    int qrow = wq * 64 + i * 16 + (lane & 15);
                    unsigned offa = ((unsigned)qrow << 7) + ((unsigned)(g ^ (qrow & 7)) << 4);
                    ah8[i] = *(const half8*)(smem + 32768 + offa);
                    al8[i] = *(const half8*)(smem + 49152 + offa);
                }
#pragma unroll
                for (int i = 0; i < 4; ++i)
#pragma unroll
                    for (int j = 0; j < 4; ++j) {
                        acc[i][j] = __builtin_amdgcn_mfma_f32_16x16x32_f16(bh8[i], ah8[j], acc[i][j], 0, 0, 0);
                        acc[i][j] = __builtin_amdgcn_mfma_f32_16x16x32_f16(bh8[i], al8[j], acc[i][j], 0, 0, 0);
                        acc[i][j] = __builtin_amdgcn_mfma_f32_16x16x32_f16(bl8[i], ah8[j], acc[i][j], 0, 0, 0);
                    }
            }
        }
    }
    int col = lane & 15, rgrp = (lane >> 4) << 2;
#pragma unroll
    for (int i = 0; i < 4; ++i) {
        int Pb = pt * 128 + wp * 64 + i * 16 + rgrp;
        float rn0 = rnorm[b * 1024 + Pb + 0];
        float rn1 = rnorm[b * 1024 + Pb + 1];
        float rn2 = rnorm[b * 1024 + Pb + 2];
        float rn3 = rnorm[b * 1024 + Pb + 3];
#pragma unroll
        for (int j = 0; j < 4; ++j) {
            int Q = qt * 128 + wq * 64 + j * 16 + col;
            float* dst = s0 + ((size_t)(b * 1024 + Pb) << 10) + Q;
            dst[0]    = acc[i][j][0] * rn0;
            dst[1024] = acc[i][j][1] * rn1;
            dst[2048] = acc[i][j][2] * rn2;
            dst[3072] = acc[i][j][3] * rn3;
        }
    }
}

__device__ __forceinline__ int untr(int v) { return (v & 31) * 32 + (v >> 5); }

// s2[b][R][T] for active R only (double diagonal fuse + flat transpose)
__global__ void k_fuse(const float* __restrict__ s0, float* __restrict__ s2,
                       const int* __restrict__ L, const int* __restrict__ nactp) {
    int nact = *nactp;
    int b = blockIdx.z;
    int T = blockIdx.x * 256 + threadIdx.x;
    const float* S = s0 + (size_t)b * 1048576;
    for (int ai = blockIdx.y; ai < nact; ai += 32) {
        int R = L[ai];
        float acc = 0.f;
#pragma unroll
        for (int k = -1; k <= 1; ++k) {
            int Rk = R + k, Tk = T + k;
            if (Rk < 0 || Rk >= 1024 || Tk < 0 || Tk >= 1024) continue;
            int Pr = untr(Rk), Qc = untr(Tk);
#pragma unroll
            for (int j = -1; j <= 1; ++j) {
                int r = Pr + j, cI = Qc + j;
                if (r < 0 || r >= 1024 || cI < 0 || cI >= 1024) continue;
                acc += S[(size_t)r * 1024 + cI];
            }
        }
        s2[(size_t)b * 1048576 + (size_t)R * 1024 + T] = acc;
    }
}

__global__ void k_soft1(const float* __restrict__ s2, const int* __restrict__ L,
                        const int* __restrict__ nactp, float* __restrict__ M,
                        float* __restrict__ den) {
    int nact = *nactp;
    int b = blockIdx.y;
    int T = blockIdx.x * 256 + threadIdx.x;
    const float* S = s2 + (size_t)b * 1048576;
    float m = -3e38f;
    for (int ai = 0; ai < nact; ++ai) m = fmaxf(m, S[(size_t)L[ai] * 1024 + T]);
    int cnt0 = 1024 - nact;
    if (cnt0 > 0) m = fmaxf(m, 0.f);
    float d = (float)cnt0 * expf(-10.f * m);
    for (int ai = 0; ai < nact; ++ai) d += expf(10.f * (S[(size_t)L[ai] * 1024 + T] - m));
    M[b * 1024 + T] = m;
    den[b * 1024 + T] = d;
}

__global__ void k_wgt(float* __restrict__ s2, const int* __restrict__ L,
                      const int* __restrict__ nactp, const float* __restrict__ M,
                      const float* __restrict__ den) {
    int nact = *nactp;
    int b = blockIdx.z;
    int T = blockIdx.x * 256 + threadIdx.x;
    for (int ai = blockIdx.y; ai < nact; ai += 32) {
        int R = L[ai];
        size_t o = (size_t)b * 1048576 + (size_t)R * 1024 + T;
        float v = s2[o];
        s2[o] = expf(10.f * (v - M[b * 1024 + T])) / den[b * 1024 + T];
    }
}

// CT[b][a*4+bb][c][ai] (f16, ai-stride 1024) = BGt[b][2hb-1+a][2wb-1+bb][c], R=L[ai]
// zero for OOB rows/cols and for ai in [nact, KPAD)
__global__ void k_ct(const ush* __restrict__ BGt, const int* __restrict__ L,
                     const int* __restrict__ nactp, ush* __restrict__ CT) {
    int nact = *nactp;
    int KPAD = (nact + 31) & ~31;
    int ab = blockIdx.x, b = blockIdx.y, t = threadIdx.x;
    int a = ab >> 2, bb = ab & 3;
    for (int ai0 = 0; ai0 < KPAD; ai0 += 256) {
        int ai = ai0 + t;
        if (ai >= KPAD) break;
        int ok = 0;
        const ush* srow = nullptr;
        if (ai < nact) {
            int R = L[ai];
            int hb = R >> 5, wb = R & 31;
            int row = 2 * hb - 1 + a, col = 2 * wb - 1 + bb;
            if (row >= 0 && row < 64 && col >= 0 && col < 64) {
                ok = 1;
                srow = BGt + ((size_t)((b * 64 + row) * 64 + col) << 7);
            }
        }
        ush* dst = CT + ((size_t)(b * 16 + ab) << 17) + ai;
#pragma unroll 4
        for (int c = 0; c < 128; ++c)
            dst[(size_t)c << 10] = ok ? srow[c] : (ush)0;
    }
}

// Deconv as parity-class GEMM: y[pix, c] = 0.25 * sum_{pp,qq} sum_ai W_shift * CT
#define WSQ 40  // ai-stride (halfs) in WS: 80B, 16B-aligned frag reads
__global__ void k_dgemm(const float* __restrict__ s2, const ush* __restrict__ CT,
                        const int* __restrict__ L, const int* __restrict__ nactp,
                        float* __restrict__ y) {
    int nact = *nactp;
    int KPAD = (nact + 31) & ~31;
    int mtile = blockIdx.x, par = blockIdx.y, b = blockIdx.z;
    int a_lo = par >> 1, b_lo = par & 1;
    int P0 = 1 - a_lo, Q0 = 1 - b_lo;
    int pb = P0 + mtile * 4;           // p_lo base of this 128-pix tile
    int t = threadIdx.x, wid = t >> 6, lane = t & 63;
    int wc = wid & 1, wp2 = wid >> 1;  // c-half, pix-half
    __shared__ ush WS[5 * 33 * WSQ];   // [p'][q'][ai]
    __shared__ int Lsh[32];

    f32x4 acc[4][4];
#pragma unroll
    for (int i = 0; i < 4; ++i)
#pragma unroll
        for (int j = 0; j < 4; ++j) acc[i][j] = (f32x4){0.f, 0.f, 0.f, 0.f};

    for (int k0 = 0; k0 < KPAD; k0 += 32) {
        __syncthreads();
        if (t < 32) Lsh[t] = (k0 + t < nact) ? L[k0 + t] : -1;
        __syncthreads();
        // stage shifted weight window: k outer so s2 reads are row-coalesced
        for (int idx = t; idx < 5280; idx += 256) {
            int k = idx / 165, rem = idx - k * 165;
            int pr = rem / 33, qi = rem - pr * 33;
            int p_ = pb - 1 + pr, q_ = Q0 - 1 + qi;
            int R = Lsh[k];
            float w = 0.f;
            if (R >= 0 && p_ >= 0 && p_ < 32 && q_ >= 0 && q_ < 32)
                w = s2[((size_t)(b * 1024 + R) << 10) + p_ * 32 + q_];
            WS[(pr * 33 + qi) * WSQ + k] = f2h(w);
        }
        __syncthreads();
        int kg = (lane >> 4) * 8;  // k offset within tile for this lane
#pragma unroll
        for (int pp = 0; pp < 2; ++pp)
#pragma unroll
            for (int qq = 0; qq < 2; ++qq) {
                int ab = (a_lo + 2 * pp) * 4 + (b_lo + 2 * qq);
                const ush* Abase = CT + ((size_t)(b * 16 + ab) << 17)
                                 + ((size_t)(wc * 64) << 10) + k0 + kg;
                half8 A[4], B[4];
#pragma unroll
                for (int i = 0; i < 4; ++i)
                    A[i] = *(const half8*)(Abase + ((size_t)(i * 16 + (lane & 15)) << 10));
#pragma unroll
                for (int j = 0; j < 4; ++j) {
                    int pr = wp2 * 2 + (j >> 1) + 1 - pp;
                    int qi = (j & 1) * 16 + (lane & 15) - qq + 1;
                    B[j] = *(const half8*)(WS + (pr * 33 + qi) * WSQ + kg);
                }
#pragma unroll
                for (int i = 0; i < 4; ++i)
#pragma unroll
                    for (int j = 0; j < 4; ++j)
                        acc[i][j] = __builtin_amdgcn_mfma_f32_16x16x32_f16(A[i], B[j], acc[i][j], 0, 0, 0);
            }
    }
    // epilogue: C row=(lane>>4)*4+r -> c, col=lane&15 -> pix
    int col = lane & 15, rgrp = (lane >> 4) << 2;
#pragma unroll
    for (int i = 0; i < 4; ++i) {
        int c = wc * 64 + i * 16 + rgrp;
#pragma unroll
        for (int j = 0; j < 4; ++j) {
            int pix = wp2 * 64 + j * 16 + col;
            int p_lo = pb + (pix >> 5);
            int q_lo = Q0 + (pix & 31);
            int oy = 2 * p_lo + a_lo - 1;
            int ox = 2 * q_lo + b_lo - 1;
            float* Y = y + ((size_t)((b * 128 + c) * 64 + oy) << 6) + ox;
            Y[0]        = acc[i][j][0] * 0.25f;
            Y[64 * 64]  = acc[i][j][1] * 0.25f;
            Y[2 * 4096] = acc[i][j][2] * 0.25f;
            Y[3 * 4096] = acc[i][j][3] * 0.25f;
        }
    }
}

extern "C" void kernel_launch(void* const* d_in, const int* in_sizes, int n_in,
                              void* d_out, int out_size, void* d_ws, size_t ws_size,
                              hipStream_t stream) {
    (void)in_sizes; (void)n_in; (void)out_size; (void)ws_size;
    const float* fg   = (const float*)d_in[0];
    const float* bg   = (const float*)d_in[1];
    const float* mask = (const float*)d_in[2];
    float* y = (float*)d_out;
    char* ws = (char*)d_ws;

    ush*   fgh   = (ush*)(ws + OFF_FGH);
    ush*   fgl   = (ush*)(ws + OFF_FGL);
    ush*   bgh   = (ush*)(ws + OFF_BGH);
    ush*   bgl   = (ush*)(ws + OFF_BGL);
    ush*   BGt   = (ush*)(ws + OFF_BGT);
    float* SS    = (float*)(ws + OFF_SS);
    float* rnorm = (float*)(ws + OFF_RN);
    float* Mb    = (float*)(ws + OFF_MM);
    float* den   = (float*)(ws + OFF_DEN);
    int*   Lst   = (int*)(ws + OFF_LIST);
    int*   nact  = (int*)(ws + OFF_NACT);
    float* s0    = (float*)(ws + OFF_S0);
    ush*   CT    = (ush*)(ws + OFF_S0);   // reuses s0 region after k_fuse
    float* s2    = (float*)(ws + OFF_S2);

    hipMemsetAsync(ws, 0, OFF_BGT, stream);  // zero padded-image borders
    k_prep<<<dim3(32, 8), 256, 0, stream>>>(fg, bg, fgh, fgl, bgh, bgl);
    k_tr<<<dim3(64, 8), 256, 0, stream>>>(bg, BGt);
    k_eqscan<<<1, 1024, 0, stream>>>(mask, Lst, nact);
    k_ss<<<32, 256, 0, stream>>>(bgh, bgl, SS);
    k_norm<<<32, 256, 0, stream>>>(SS, rnorm);
    k_smfma<<<dim3(8, 8, 8), 256, 0, stream>>>(fgh, fgl, bgh, bgl, rnorm, s0);
    k_fuse<<<dim3(4, 32, 8), 256, 0, stream>>>(s0, s2, Lst, nact);
    k_ct<<<dim3(16, 8), 256, 0, stream>>>(BGt, Lst, nact, CT);
    k_soft1<<<dim3(4, 8), 256, 0, stream>>>(s2, Lst, nact, Mb, den);
    k_wgt<<<dim3(4, 32, 8), 256, 0, stream>>>(s2, Lst, nact, Mb, den);
    k_dgemm<<<dim3(8, 4, 8), 256, 0, stream>>>(s2, CT, Lst, nact, y);
}

// Round 4
// 173.553 us; speedup vs baseline: 3.9023x; 1.1370x over previous
//
#include <hip/hip_runtime.h>

typedef _Float16 half8 __attribute__((ext_vector_type(8)));
typedef float f32x4 __attribute__((ext_vector_type(4)));
typedef unsigned short us8 __attribute__((ext_vector_type(8)));
typedef unsigned short ush;
typedef unsigned int uint32;

#define IMGB 295936u   // bytes per padded per-batch image (34*34*128*2)
#define WROW 8704u     // bytes per padded image row (34*128*2)

// workspace byte offsets
#define OFF_FGH  0ull
#define OFF_BGH  2367488ull
#define OFF_BGL  4734976ull
#define OFF_BGT  7102464ull
#define OFF_RN   15491072ull
#define OFF_MM   15523840ull
#define OFF_RD   15556608ull
#define OFF_LIST 15589376ull
#define OFF_NACT 15593472ull
#define OFF_S0   15597568ull   // 32 MB: s0 scores, reused as CT after k_fuse
#define OFF_S2   49152000ull   // 32 MB: s2t (u-relabeled)
// end 82,706,432 bytes

static __device__ __forceinline__ ush f2h(float f) {
    union { _Float16 h; ush u; } c; c.h = (_Float16)f; return c.u;
}
static __device__ __forceinline__ float h2f(ush u) {
    union { _Float16 h; ush u; } c; c.u = u; return (float)c.h;
}
__device__ __forceinline__ int untr(int v) { return ((v & 31) << 5) | (v >> 5); }

// fg/bg fp32 [b][c][64][64] -> downsampled padded f16 {fg_hi, bg_hi, bg_lo} [b][34][34][128]
// borders zeroed inline (no memset needed)
__global__ void k_prep(const float* __restrict__ fg, const float* __restrict__ bg,
                       ush* __restrict__ fgh, ush* __restrict__ bgh, ush* __restrict__ bgl) {
    int y = blockIdx.x, b = blockIdx.y, t = threadIdx.x;
    int xq = t & 31, cg = t >> 5;
    __shared__ ush lfh[32][130], lbh[32][130], lbl[32][130];
    for (int c0 = 0; c0 < 128; c0 += 8) {
        int c = c0 + cg;
        int src = ((b * 128 + c) * 64 + 2 * y) * 64 + 2 * xq;
        float vf = fg[src], vb = bg[src];
        _Float16 bh = (_Float16)vb; float br = vb - (float)bh;
        union { _Float16 h; ush u; } c1, c3, c4;
        c1.h = (_Float16)vf; c3.h = bh; c4.h = (_Float16)br;
        lfh[xq][c] = c1.u; lbh[xq][c] = c3.u; lbl[xq][c] = c4.u;
    }
    __syncthreads();
    unsigned base = ((b * 34 + y + 1) * 34 + 1) * 128;  // half index
    for (int k = t; k < 2048; k += 256) {               // uint index
        int x = k >> 6, cp = (k & 63) * 2;
        ((uint32*)(fgh + base))[k] = *(const uint32*)&lfh[x][cp];
        ((uint32*)(bgh + base))[k] = *(const uint32*)&lbh[x][cp];
        ((uint32*)(bgl + base))[k] = *(const uint32*)&lbl[x][cp];
    }
    // zero col borders of this row (x=0 and x=33), 128 halfs = 64 uints each
    unsigned cb0 = ((unsigned)(b * 34 + y + 1) * 34) * 64;        // uint index
    if (t < 64) {
        ((uint32*)fgh)[cb0 + t] = 0; ((uint32*)bgh)[cb0 + t] = 0; ((uint32*)bgl)[cb0 + t] = 0;
    } else if (t < 128) {
        unsigned cb1 = cb0 + 33 * 64 + (t - 64);
        ((uint32*)fgh)[cb1] = 0; ((uint32*)bgh)[cb1] = 0; ((uint32*)bgl)[cb1] = 0;
    }
    // zero full top/bottom border rows
    if (y == 0 || y == 31) {
        int prow = (y == 0) ? 0 : 33;
        unsigned rb = (unsigned)(b * 34 + prow) * 2176;  // uint index
        for (int k = t; k < 2176; k += 256) {
            ((uint32*)fgh)[rb + k] = 0; ((uint32*)bgh)[rb + k] = 0; ((uint32*)bgl)[rb + k] = 0;
        }
    }
}

// BGt[b][y][x][c] (f16) = background[b][c][y][x], full resolution
__global__ void k_tr(const float* __restrict__ bg, ush* __restrict__ BGt) {
    int b = blockIdx.y, y = blockIdx.x, t = threadIdx.x;
    __shared__ float lds[64 * 129];
    int xx = t & 63;
    for (int c0 = 0; c0 < 128; c0 += 4) {
        int c = c0 + (t >> 6);
        lds[xx * 129 + c] = bg[((b * 128 + c) * 64 + y) * 64 + xx];
    }
    __syncthreads();
    uint32* dst = (uint32*)(BGt + (size_t)(b * 64 + y) * 8192);
    for (int j = t; j < 4096; j += 256) {
        int x = j >> 6, cp = (j & 63) * 2;
        uint32 h0 = f2h(lds[x * 129 + cp]);
        uint32 h1 = f2h(lds[x * 129 + cp + 1]);
        dst[j] = h0 | (h1 << 16);
    }
}

// eq flags + deterministic compaction (single block, 1024 threads)
__global__ void k_eqscan(const float* __restrict__ mask, int* __restrict__ L,
                         int* __restrict__ nact) {
    __shared__ int f[1024], sc[1024];
    int l = threadIdx.x;
    int hm = l >> 5, wm = l & 31;
    int any = 0;
    for (int di = -1; di <= 1; ++di)
        for (int dj = -1; dj <= 1; ++dj) {
            int yy = hm + di, xx = wm + dj;
            if (yy >= 0 && yy < 32 && xx >= 0 && xx < 32)
                any |= (mask[(2 * yy) * 64 + 2 * xx] != 0.0f);
        }
    f[l] = !any; sc[l] = f[l];
    __syncthreads();
    for (int off = 1; off < 1024; off <<= 1) {
        int v = (l >= off) ? sc[l - off] : 0;
        __syncthreads();
        sc[l] += v;
        __syncthreads();
    }
    if (f[l]) L[sc[l] - 1] = l;
    if (l == 1023) nact[0] = sc[1023];
}

// merged SS + norm: block = (rq, b); computes rnorm for 8 P-rows using 10 SS rows in LDS
__global__ void k_ssn(const ush* __restrict__ bgh, const ush* __restrict__ bgl,
                      float* __restrict__ rnorm) {
    int rq = blockIdx.x, b = blockIdx.y, t = threadIdx.x;
    int r0 = rq * 8;
    __shared__ float ssh[10][32];
    for (int idx = t; idx < 320; idx += 256) {
        int row = idx >> 5, xx = idx & 31;
        int gy = r0 - 1 + row;
        float s = 0.f;
        if (gy >= 0 && gy < 32) {
            size_t base = ((size_t)(b * 34 + gy + 1) * 34 + xx + 1) * 128;
            for (int c = 0; c < 128; c += 8) {
                us8 vh = *(const us8*)(bgh + base + c);
                us8 vl = *(const us8*)(bgl + base + c);
#pragma unroll
                for (int j = 0; j < 8; ++j) {
                    float v = h2f(vh[j]) + h2f(vl[j]);
                    s += v * v;
                }
            }
        }
        ssh[row][xx] = s;
    }
    __syncthreads();
    int pr = t >> 5, pc = t & 31;
    float n2 = 0.f;
#pragma unroll
    for (int di = -1; di <= 1; ++di)
#pragma unroll
        for (int dj = -1; dj <= 1; ++dj) {
            int xx = pc + dj;
            if (xx >= 0 && xx < 32) n2 += ssh[pr + 1 + di][xx];
        }
    rnorm[b * 1024 + (r0 + pr) * 32 + pc] = 1.0f / fmaxf(sqrtf(n2), 1e-4f);
}

// MFMA score, stage-once window version, 2-pass hi/lo (bg split, fg single f16)
__global__ __launch_bounds__(256)
void k_smfma(const ush* __restrict__ fgh, const ush* __restrict__ bgh,
             const ush* __restrict__ bgl, const float* __restrict__ rnorm,
             float* __restrict__ s0) {
    int qt = blockIdx.x, pt = blockIdx.y, b = blockIdx.z;
    int t = threadIdx.x, wid = t >> 6, lane = t & 63;
    int wp = wid >> 1, wq = wid & 1;
    __shared__ ulong2 smem_raw[9792];   // 156672 B = 3 x 52224 (bgh | bgl | fgh windows)
    char* smem = (char*)smem_raw;

    // stage 3 slabs (6 rows x 34 x 128 each), slot-XOR pre-swizzled global source
    {
        const char* base0 = (const char*)bgh + (size_t)b * IMGB + (unsigned)(pt * 4) * WROW;
        const char* base1 = (const char*)bgl + (size_t)b * IMGB + (unsigned)(pt * 4) * WROW;
        const char* base2 = (const char*)fgh + (size_t)b * IMGB + (unsigned)(qt * 4) * WROW;
        int sl = lane & 15;
        for (int idx = wid; idx < 153; idx += 4) {
            int a = idx / 51;
            int chunk = idx - a * 51;
            int pix = chunk * 4 + (lane >> 4);          // 0..203
            int g = sl ^ (pix & 7);
            const char* sb = (a == 0) ? base0 : (a == 1) ? base1 : base2;
            const char* gp = sb + ((unsigned)pix << 8) + ((unsigned)g << 4);
            char* lp = smem + ((unsigned)idx << 10);    // wave-uniform; HW adds lane*16
            __builtin_amdgcn_global_load_lds(
                (const __attribute__((address_space(1))) void*)gp,
                (__attribute__((address_space(3))) void*)lp, 16, 0, 0);
        }
    }
    __syncthreads();

    f32x4 acc[4][4];
#pragma unroll
    for (int i = 0; i < 4; ++i)
#pragma unroll
        for (int j = 0; j < 4; ++j) acc[i][j] = (f32x4){0.f, 0.f, 0.f, 0.f};

    int r15 = lane & 15, hi2 = lane >> 4;
    for (int o = 0; o < 9; ++o) {
        int dy = o / 3, dx = o - 3 * (o / 3);   // 0..2 (already +1-shifted)
        int pixB[4], pixA[4];
#pragma unroll
        for (int i = 0; i < 4; ++i) {
            pixB[i] = (wp * 2 + (i >> 1) + dy) * 34 + (i & 1) * 16 + r15 + dx;
            pixA[i] = (wq * 2 + (i >> 1) + dy) * 34 + (i & 1) * 16 + r15 + dx;
        }
#pragma unroll
        for (int cc = 0; cc < 4; ++cc) {
            int g = cc * 4 + hi2;
            half8 bh[4], bl[4], af[4];
#pragma unroll
            for (int i = 0; i < 4; ++i) {
                unsigned offB = ((unsigned)pixB[i] << 8) + ((unsigned)(g ^ (pixB[i] & 7)) << 4);
                bh[i] = *(const half8*)(smem + offB);
                bl[i] = *(const half8*)(smem + 52224 + offB);
                unsigned offA = ((unsigned)pixA[i] << 8) + ((unsigned)(g ^ (pixA[i] & 7)) << 4);
                af[i] = *(const half8*)(smem + 104448 + offA);
            }
#pragma unroll
            for (int i = 0; i < 4; ++i)
#pragma unroll
                for (int j = 0; j < 4; ++j) {
                    acc[i][j] = __builtin_amdgcn_mfma_f32_16x16x32_f16(bh[i], af[j], acc[i][j], 0, 0, 0);
                    acc[i][j] = __builtin_amdgcn_mfma_f32_16x16x32_f16(bl[i], af[j], acc[i][j], 0, 0, 0);
                }
        }
    }
    // epilogue: C row=(lane>>4)*4+reg <-> P (bg), col=lane&15 <-> Q (fg)
    int col = lane & 15, rgrp = (lane >> 4) << 2;
#pragma unroll
    for (int i = 0; i < 4; ++i) {
        int Pb = pt * 128 + wp * 64 + i * 16 + rgrp;
        float rn0 = rnorm[b * 1024 + Pb + 0];
        float rn1 = rnorm[b * 1024 + Pb + 1];
        float rn2 = rnorm[b * 1024 + Pb + 2];
        float rn3 = rnorm[b * 1024 + Pb + 3];
#pragma unroll
        for (int j = 0; j < 4; ++j) {
            int Q = qt * 128 + wq * 64 + j * 16 + col;
            float* dst = s0 + ((size_t)(b * 1024 + Pb) << 10) + Q;
            dst[0]    = acc[i][j][0] * rn0;
            dst[1024] = acc[i][j][1] * rn1;
            dst[2048] = acc[i][j][2] * rn2;
            dst[3072] = acc[i][j][3] * rn3;
        }
    }
}

// s2t[b][R][u] = fuse(s0) at T=untr(u); u-enumeration makes reads AND writes coalesced
__global__ void k_fuse(const float* __restrict__ s0, float* __restrict__ s2t,
                       const int* __restrict__ L, const int* __restrict__ nactp) {
    int nact = *nactp;
    int b = blockIdx.z;
    int u = blockIdx.x * 256 + threadIdx.x;
    int T = untr(u);
    const float* S = s0 + (size_t)b * 1048576;
    for (int ai = blockIdx.y; ai < nact; ai += 32) {
        int R = L[ai];
        float acc = 0.f;
#pragma unroll
        for (int k = -1; k <= 1; ++k) {
            int Rk = R + k, Tk = T + k;
            if ((unsigned)Rk < 1024u && (unsigned)Tk < 1024u) {
                int Pr = untr(Rk), Qc = untr(Tk);
#pragma unroll
                for (int j = -1; j <= 1; ++j) {
                    int r = Pr + j, cI = Qc + j;
                    if ((unsigned)r < 1024u && (unsigned)cI < 1024u)
                        acc += S[(size_t)r * 1024 + cI];
                }
            }
        }
        s2t[(size_t)b * 1048576 + (size_t)R * 1024 + u] = acc;
    }
}

// online softmax stats over active R per (b,u); stores max and 1/denom
__global__ void k_soft1(const float* __restrict__ s2t, const int* __restrict__ L,
                        const int* __restrict__ nactp, float* __restrict__ M,
                        float* __restrict__ RD) {
    int nact = *nactp;
    int b = blockIdx.y;
    int u = blockIdx.x * 256 + threadIdx.x;
    const float* S = s2t + (size_t)b * 1048576 + u;
    float m = -3e38f, d = 0.f;
    for (int ai = 0; ai < nact; ++ai) {
        float v = S[(size_t)L[ai] * 1024];
        if (v > m) { d *= expf(10.f * (m - v)); m = v; }
        d += expf(10.f * (v - m));
    }
    int cnt0 = 1024 - nact;
    if (cnt0 > 0) {
        if (m < 0.f) { d *= expf(10.f * m); m = 0.f; }
        d += (float)cnt0 * expf(-10.f * m);
    }
    M[b * 1024 + u] = m;
    RD[b * 1024 + u] = 1.f / d;
}

// CT[b][a*4+bb][c][ai] (f16, ai-stride 256) = BGt[b][2hb-1+a][2wb-1+bb][c], R=L[ai]
#define CTK 256
__global__ void k_ct(const ush* __restrict__ BGt, const int* __restrict__ L,
                     const int* __restrict__ nactp, ush* __restrict__ CT) {
    int nact = *nactp;
    int KPAD = (nact + 31) & ~31;
    int ab = blockIdx.x, b = blockIdx.y, t = threadIdx.x;
    int a = ab >> 2, bb = ab & 3;
    for (int ai0 = 0; ai0 < KPAD; ai0 += 256) {
        int ai = ai0 + t;
        if (ai >= KPAD) break;
        int ok = 0;
        const ush* srow = nullptr;
        if (ai < nact) {
            int R = L[ai];
            int hb = R >> 5, wb = R & 31;
            int row = 2 * hb - 1 + a, col = 2 * wb - 1 + bb;
            if (row >= 0 && row < 64 && col >= 0 && col < 64) {
                ok = 1;
                srow = BGt + ((size_t)((b * 64 + row) * 64 + col) << 7);
            }
        }
        ush* dst = CT + ((size_t)(b * 16 + ab) << 15) + ai;
#pragma unroll 4
        for (int c = 0; c < 128; ++c)
            dst[(size_t)c << 8] = ok ? srow[c] : (ush)0;
    }
}

// Deconv as parity-class GEMM; weight staging applies exp/denominator inline
#define WSQ 40  // ai-stride (halfs) in WS
__global__ void k_dgemm(const float* __restrict__ s2t, const ush* __restrict__ CT,
                        const int* __restrict__ L, const int* __restrict__ nactp,
                        const float* __restrict__ M, const float* __restrict__ RD,
                        float* __restrict__ y) {
    int nact = *nactp;
    int KPAD = (nact + 31) & ~31;
    int mtile = blockIdx.x, par = blockIdx.y, b = blockIdx.z;
    int a_lo = par >> 1, b_lo = par & 1;
    int P0 = 1 - a_lo, Q0 = 1 - b_lo;
    int pb = P0 + mtile * 4;
    int t = threadIdx.x, wid = t >> 6, lane = t & 63;
    int wc = wid & 1, wp2 = wid >> 1;
    __shared__ ush WS[5 * 33 * WSQ];
    __shared__ int Lsh[32];

    f32x4 acc[4][4];
#pragma unroll
    for (int i = 0; i < 4; ++i)
#pragma unroll
        for (int j = 0; j < 4; ++j) acc[i][j] = (f32x4){0.f, 0.f, 0.f, 0.f};

    for (int k0 = 0; k0 < KPAD; k0 += 32) {
        __syncthreads();
        if (t < 32) Lsh[t] = (k0 + t < nact) ? L[k0 + t] : -1;
        __syncthreads();
        for (int idx = t; idx < 5280; idx += 256) {
            int k = idx / 165, rem = idx - k * 165;
            int pr = rem / 33, qi = rem - pr * 33;
            int p_ = pb - 1 + pr, q_ = Q0 - 1 + qi;
            int R = Lsh[k];
            float w = 0.f;
            if (R >= 0 && (unsigned)p_ < 32u && (unsigned)q_ < 32u) {
                int u_ = q_ * 32 + p_;
                float v = s2t[((size_t)(b * 1024 + R) << 10) + u_];
                w = expf(10.f * (v - M[b * 1024 + u_])) * RD[b * 1024 + u_];
            }
            WS[(pr * 33 + qi) * WSQ + k] = f2h(w);
        }
        __syncthreads();
        int kg = (lane >> 4) * 8;
#pragma unroll
        for (int pp = 0; pp < 2; ++pp)
#pragma unroll
            for (int qq = 0; qq < 2; ++qq) {
                int ab = (a_lo + 2 * pp) * 4 + (b_lo + 2 * qq);
                const ush* Abase = CT + ((size_t)(b * 16 + ab) << 15)
                                 + ((size_t)(wc * 64) << 8) + k0 + kg;
                half8 A[4], B[4];
#pragma unroll
                for (int i = 0; i < 4; ++i)
                    A[i] = *(const half8*)(Abase + ((size_t)(i * 16 + (lane & 15)) << 8));
#pragma unroll
                for (int j = 0; j < 4; ++j) {
                    int pr = wp2 * 2 + (j >> 1) + 1 - pp;
                    int qi = (j & 1) * 16 + (lane & 15) - qq + 1;
                    B[j] = *(const half8*)(WS + (pr * 33 + qi) * WSQ + kg);
                }
#pragma unroll
                for (int i = 0; i < 4; ++i)
#pragma unroll
                    for (int j = 0; j < 4; ++j)
                        acc[i][j] = __builtin_amdgcn_mfma_f32_16x16x32_f16(A[i], B[j], acc[i][j], 0, 0, 0);
            }
    }
    int col = lane & 15, rgrp = (lane >> 4) << 2;
#pragma unroll
    for (int i = 0; i < 4; ++i) {
        int c = wc * 64 + i * 16 + rgrp;
#pragma unroll
        for (int j = 0; j < 4; ++j) {
            int pix = wp2 * 64 + j * 16 + col;
            int p_lo = pb + (pix >> 5);
            int q_lo = Q0 + (pix & 31);
            int oy = 2 * p_lo + a_lo - 1;
            int ox = 2 * q_lo + b_lo - 1;
            float* Y = y + ((size_t)((b * 128 + c) * 64 + oy) << 6) + ox;
            Y[0]        = acc[i][j][0] * 0.25f;
            Y[64 * 64]  = acc[i][j][1] * 0.25f;
            Y[2 * 4096] = acc[i][j][2] * 0.25f;
            Y[3 * 4096] = acc[i][j][3] * 0.25f;
        }
    }
}

extern "C" void kernel_launch(void* const* d_in, const int* in_sizes, int n_in,
                              void* d_out, int out_size, void* d_ws, size_t ws_size,
                              hipStream_t stream) {
    (void)in_sizes; (void)n_in; (void)out_size; (void)ws_size;
    const float* fg   = (const float*)d_in[0];
    const float* bg   = (const float*)d_in[1];
    const float* mask = (const float*)d_in[2];
    float* y = (float*)d_out;
    char* ws = (char*)d_ws;

    ush*   fgh   = (ush*)(ws + OFF_FGH);
    ush*   bgh   = (ush*)(ws + OFF_BGH);
    ush*   bgl   = (ush*)(ws + OFF_BGL);
    ush*   BGt   = (ush*)(ws + OFF_BGT);
    float* rnorm = (float*)(ws + OFF_RN);
    float* Mb    = (float*)(ws + OFF_MM);
    float* RD    = (float*)(ws + OFF_RD);
    int*   Lst   = (int*)(ws + OFF_LIST);
    int*   nact  = (int*)(ws + OFF_NACT);
    float* s0    = (float*)(ws + OFF_S0);
    ush*   CT    = (ush*)(ws + OFF_S0);   // aliases s0 after k_fuse
    float* s2t   = (float*)(ws + OFF_S2);

    k_prep<<<dim3(32, 8), 256, 0, stream>>>(fg, bg, fgh, bgh, bgl);
    k_tr<<<dim3(64, 8), 256, 0, stream>>>(bg, BGt);
    k_eqscan<<<1, 1024, 0, stream>>>(mask, Lst, nact);
    k_ssn<<<dim3(4, 8), 256, 0, stream>>>(bgh, bgl, rnorm);
    k_smfma<<<dim3(8, 8, 8), 256, 0, stream>>>(fgh, bgh, bgl, rnorm, s0);
    k_fuse<<<dim3(4, 32, 8), 256, 0, stream>>>(s0, s2t, Lst, nact);
    k_ct<<<dim3(16, 8), 256, 0, stream>>>(BGt, Lst, nact, CT);
    k_soft1<<<dim3(4, 8), 256, 0, stream>>>(s2t, Lst, nact, Mb, RD);
    k_dgemm<<<dim3(8, 4, 8), 256, 0, stream>>>(s2t, CT, Lst, nact, Mb, RD, y);
}

// Round 5
// 164.555 us; speedup vs baseline: 4.1157x; 1.0547x over previous
//
#include <hip/hip_runtime.h>

typedef _Float16 half8 __attribute__((ext_vector_type(8)));
typedef float f32x4 __attribute__((ext_vector_type(4)));
typedef unsigned short us8 __attribute__((ext_vector_type(8)));
typedef unsigned short ush;
typedef unsigned int uint32;

#define IMGB 295936u   // bytes per padded per-batch image (34*34*128*2)
#define WROW 8704u     // bytes per padded image row (34*128*2)

// workspace byte offsets
#define OFF_FGH  0ull
#define OFF_BGH  2367488ull
#define OFF_BGL  4734976ull
#define OFF_BGT  7102464ull
#define OFF_RN   15491072ull
#define OFF_MM   15523840ull
#define OFF_RD   15556608ull
#define OFF_LIST 15589376ull
#define OFF_NACT 15593472ull
#define OFF_S0   15597568ull   // 32 MB: s0 scores, reused as CT after k_fuse
#define OFF_S2   49152000ull   // 32 MB: s2t (u-relabeled)
// end 82,706,432 bytes

static __device__ __forceinline__ ush f2h(float f) {
    union { _Float16 h; ush u; } c; c.h = (_Float16)f; return c.u;
}
static __device__ __forceinline__ float h2f(ush u) {
    union { _Float16 h; ush u; } c; c.u = u; return (float)c.h;
}
__device__ __forceinline__ int untr(int v) { return ((v & 31) << 5) | (v >> 5); }

// fg/bg fp32 [b][c][64][64] -> downsampled padded f16 {fg_hi, bg_hi, bg_lo} [b][34][34][128]
// borders zeroed inline (no memset needed)
__global__ void k_prep(const float* __restrict__ fg, const float* __restrict__ bg,
                       ush* __restrict__ fgh, ush* __restrict__ bgh, ush* __restrict__ bgl) {
    int y = blockIdx.x, b = blockIdx.y, t = threadIdx.x;
    int xq = t & 31, cg = t >> 5;
    __shared__ ush lfh[32][130], lbh[32][130], lbl[32][130];
    for (int c0 = 0; c0 < 128; c0 += 8) {
        int c = c0 + cg;
        int src = ((b * 128 + c) * 64 + 2 * y) * 64 + 2 * xq;
        float vf = fg[src], vb = bg[src];
        _Float16 bh = (_Float16)vb; float br = vb - (float)bh;
        union { _Float16 h; ush u; } c1, c3, c4;
        c1.h = (_Float16)vf; c3.h = bh; c4.h = (_Float16)br;
        lfh[xq][c] = c1.u; lbh[xq][c] = c3.u; lbl[xq][c] = c4.u;
    }
    __syncthreads();
    unsigned base = ((b * 34 + y + 1) * 34 + 1) * 128;  // half index
    for (int k = t; k < 2048; k += 256) {               // uint index
        int x = k >> 6, cp = (k & 63) * 2;
        ((uint32*)(fgh + base))[k] = *(const uint32*)&lfh[x][cp];
        ((uint32*)(bgh + base))[k] = *(const uint32*)&lbh[x][cp];
        ((uint32*)(bgl + base))[k] = *(const uint32*)&lbl[x][cp];
    }
    // zero col borders of this row (x=0 and x=33), 128 halfs = 64 uints each
    unsigned cb0 = ((unsigned)(b * 34 + y + 1) * 34) * 64;        // uint index
    if (t < 64) {
        ((uint32*)fgh)[cb0 + t] = 0; ((uint32*)bgh)[cb0 + t] = 0; ((uint32*)bgl)[cb0 + t] = 0;
    } else if (t < 128) {
        unsigned cb1 = cb0 + 33 * 64 + (t - 64);
        ((uint32*)fgh)[cb1] = 0; ((uint32*)bgh)[cb1] = 0; ((uint32*)bgl)[cb1] = 0;
    }
    // zero full top/bottom border rows
    if (y == 0 || y == 31) {
        int prow = (y == 0) ? 0 : 33;
        unsigned rb = (unsigned)(b * 34 + prow) * 2176;  // uint index
        for (int k = t; k < 2176; k += 256) {
            ((uint32*)fgh)[rb + k] = 0; ((uint32*)bgh)[rb + k] = 0; ((uint32*)bgl)[rb + k] = 0;
        }
    }
}

// BGt[b][y][x][c] (f16) = background[b][c][y][x], full resolution
__global__ void k_tr(const float* __restrict__ bg, ush* __restrict__ BGt) {
    int b = blockIdx.y, y = blockIdx.x, t = threadIdx.x;
    __shared__ float lds[64 * 129];
    int xx = t & 63;
    for (int c0 = 0; c0 < 128; c0 += 4) {
        int c = c0 + (t >> 6);
        lds[xx * 129 + c] = bg[((b * 128 + c) * 64 + y) * 64 + xx];
    }
    __syncthreads();
    uint32* dst = (uint32*)(BGt + (size_t)(b * 64 + y) * 8192);
    for (int j = t; j < 4096; j += 256) {
        int x = j >> 6, cp = (j & 63) * 2;
        uint32 h0 = f2h(lds[x * 129 + cp]);
        uint32 h1 = f2h(lds[x * 129 + cp + 1]);
        dst[j] = h0 | (h1 << 16);
    }
}

// eq flags + deterministic compaction (single block, 1024 threads)
__global__ void k_eqscan(const float* __restrict__ mask, int* __restrict__ L,
                         int* __restrict__ nact) {
    __shared__ int f[1024], sc[1024];
    int l = threadIdx.x;
    int hm = l >> 5, wm = l & 31;
    int any = 0;
    for (int di = -1; di <= 1; ++di)
        for (int dj = -1; dj <= 1; ++dj) {
            int yy = hm + di, xx = wm + dj;
            if (yy >= 0 && yy < 32 && xx >= 0 && xx < 32)
                any |= (mask[(2 * yy) * 64 + 2 * xx] != 0.0f);
        }
    f[l] = !any; sc[l] = f[l];
    __syncthreads();
    for (int off = 1; off < 1024; off <<= 1) {
        int v = (l >= off) ? sc[l - off] : 0;
        __syncthreads();
        sc[l] += v;
        __syncthreads();
    }
    if (f[l]) L[sc[l] - 1] = l;
    if (l == 1023) nact[0] = sc[1023];
}

// merged SS + norm: block = (rq, b); computes rnorm for 8 P-rows using 10 SS rows in LDS
__global__ void k_ssn(const ush* __restrict__ bgh, const ush* __restrict__ bgl,
                      float* __restrict__ rnorm) {
    int rq = blockIdx.x, b = blockIdx.y, t = threadIdx.x;
    int r0 = rq * 8;
    __shared__ float ssh[10][32];
    for (int idx = t; idx < 320; idx += 256) {
        int row = idx >> 5, xx = idx & 31;
        int gy = r0 - 1 + row;
        float s = 0.f;
        if (gy >= 0 && gy < 32) {
            size_t base = ((size_t)(b * 34 + gy + 1) * 34 + xx + 1) * 128;
            for (int c = 0; c < 128; c += 8) {
                us8 vh = *(const us8*)(bgh + base + c);
                us8 vl = *(const us8*)(bgl + base + c);
#pragma unroll
                for (int j = 0; j < 8; ++j) {
                    float v = h2f(vh[j]) + h2f(vl[j]);
                    s += v * v;
                }
            }
        }
        ssh[row][xx] = s;
    }
    __syncthreads();
    int pr = t >> 5, pc = t & 31;
    float n2 = 0.f;
#pragma unroll
    for (int di = -1; di <= 1; ++di)
#pragma unroll
        for (int dj = -1; dj <= 1; ++dj) {
            int xx = pc + dj;
            if (xx >= 0 && xx < 32) n2 += ssh[pr + 1 + di][xx];
        }
    rnorm[b * 1024 + (r0 + pr) * 32 + pc] = 1.0f / fmaxf(sqrtf(n2), 1e-4f);
}

// MFMA score, c-split stage-once window version (2 phases of 64 ch), 2-pass hi/lo.
// LDS = 3 x 26624 B = 79872 B -> 2 blocks/CU, 2 waves/SIMD.
__global__ __launch_bounds__(256, 2)
void k_smfma(const ush* __restrict__ fgh, const ush* __restrict__ bgh,
             const ush* __restrict__ bgl, const float* __restrict__ rnorm,
             float* __restrict__ s0) {
    int qt = blockIdx.x, pt = blockIdx.y, b = blockIdx.z;
    int t = threadIdx.x, wid = t >> 6, lane = t & 63;
    int wp = wid >> 1, wq = wid & 1;
    __shared__ ulong2 smem_raw[4992];   // 79872 B: bgh | bgl | fgh half-slabs (26624 each)
    char* smem = (char*)smem_raw;

    const char* base0 = (const char*)bgh + (size_t)b * IMGB + (unsigned)(pt * 4) * WROW;
    const char* base1 = (const char*)bgl + (size_t)b * IMGB + (unsigned)(pt * 4) * WROW;
    const char* base2 = (const char*)fgh + (size_t)b * IMGB + (unsigned)(qt * 4) * WROW;

    f32x4 acc[4][4];
#pragma unroll
    for (int i = 0; i < 4; ++i)
#pragma unroll
        for (int j = 0; j < 4; ++j) acc[i][j] = (f32x4){0.f, 0.f, 0.f, 0.f};

    int r15 = lane & 15, hi2 = lane >> 4;
    for (int ch = 0; ch < 2; ++ch) {
        __syncthreads();
        // stage 3 half-slabs: 26 chunks each (208 px; 204 used), 1 KB per wave-inst
        {
            int pixl = (lane >> 3);                  // 0..7 within chunk
            int sl = lane & 7;
            for (int idx = wid; idx < 78; idx += 4) {
                int a = idx / 26;
                int chunk = idx - a * 26;
                int pix = chunk * 8 + pixl;          // 0..207
                int g = sl ^ (pix & 7);
                const char* sb = (a == 0) ? base0 : (a == 1) ? base1 : base2;
                const char* gp = sb + ((unsigned)pix << 8) + ((unsigned)ch << 7)
                               + ((unsigned)g << 4);
                char* lp = smem + (unsigned)(a * 26624 + chunk * 1024);  // + lane*16 by HW
                __builtin_amdgcn_global_load_lds(
                    (const __attribute__((address_space(1))) void*)gp,
                    (__attribute__((address_space(3))) void*)lp, 16, 0, 0);
            }
        }
        __syncthreads();

        for (int o = 0; o < 9; ++o) {
            int dy = o / 3, dx = o - 3 * (o / 3);   // 0..2 (already +1-shifted)
            int pixB[4], pixA[4];
#pragma unroll
            for (int i = 0; i < 4; ++i) {
                pixB[i] = (wp * 2 + (i >> 1) + dy) * 34 + (i & 1) * 16 + r15 + dx;
                pixA[i] = (wq * 2 + (i >> 1) + dy) * 34 + (i & 1) * 16 + r15 + dx;
            }
#pragma unroll
            for (int cc = 0; cc < 2; ++cc) {
                int g = cc * 4 + hi2;               // 0..7 c-groups of this half
                half8 bh[4], bl[4], af[4];
#pragma unroll
                for (int i = 0; i < 4; ++i) {
                    unsigned offB = ((unsigned)pixB[i] << 7) + ((unsigned)(g ^ (pixB[i] & 7)) << 4);
                    bh[i] = *(const half8*)(smem + offB);
                    bl[i] = *(const half8*)(smem + 26624 + offB);
                    unsigned offA = ((unsigned)pixA[i] << 7) + ((unsigned)(g ^ (pixA[i] & 7)) << 4);
                    af[i] = *(const half8*)(smem + 53248 + offA);
                }
#pragma unroll
                for (int i = 0; i < 4; ++i)
#pragma unroll
                    for (int j = 0; j < 4; ++j) {
                        acc[i][j] = __builtin_amdgcn_mfma_f32_16x16x32_f16(bh[i], af[j], acc[i][j], 0, 0, 0);
                        acc[i][j] = __builtin_amdgcn_mfma_f32_16x16x32_f16(bl[i], af[j], acc[i][j], 0, 0, 0);
                    }
            }
        }
    }
    // epilogue: C row=(lane>>4)*4+reg <-> P (bg), col=lane&15 <-> Q (fg)
    int col = lane & 15, rgrp = (lane >> 4) << 2;
#pragma unroll
    for (int i = 0; i < 4; ++i) {
        int Pb = pt * 128 + wp * 64 + i * 16 + rgrp;
        float rn0 = rnorm[b * 1024 + Pb + 0];
        float rn1 = rnorm[b * 1024 + Pb + 1];
        float rn2 = rnorm[b * 1024 + Pb + 2];
        float rn3 = rnorm[b * 1024 + Pb + 3];
#pragma unroll
        for (int j = 0; j < 4; ++j) {
            int Q = qt * 128 + wq * 64 + j * 16 + col;
            float* dst = s0 + ((size_t)(b * 1024 + Pb) << 10) + Q;
            dst[0]    = acc[i][j][0] * rn0;
            dst[1024] = acc[i][j][1] * rn1;
            dst[2048] = acc[i][j][2] * rn2;
            dst[3072] = acc[i][j][3] * rn3;
        }
    }
}

// s2t[b][R][u] = fuse(s0) at T=untr(u); u-enumeration makes reads AND writes coalesced
__global__ void k_fuse(const float* __restrict__ s0, float* __restrict__ s2t,
                       const int* __restrict__ L, const int* __restrict__ nactp) {
    int nact = *nactp;
    int b = blockIdx.z;
    int u = blockIdx.x * 256 + threadIdx.x;
    int T = untr(u);
    const float* S = s0 + (size_t)b * 1048576;
    for (int ai = blockIdx.y; ai < nact; ai += 32) {
        int R = L[ai];
        float acc = 0.f;
#pragma unroll
        for (int k = -1; k <= 1; ++k) {
            int Rk = R + k, Tk = T + k;
            if ((unsigned)Rk < 1024u && (unsigned)Tk < 1024u) {
                int Pr = untr(Rk), Qc = untr(Tk);
#pragma unroll
                for (int j = -1; j <= 1; ++j) {
                    int r = Pr + j, cI = Qc + j;
                    if ((unsigned)r < 1024u && (unsigned)cI < 1024u)
                        acc += S[(size_t)r * 1024 + cI];
                }
            }
        }
        s2t[(size_t)b * 1048576 + (size_t)R * 1024 + u] = acc;
    }
}

// online softmax stats over active R per (b,u); stores max and 1/denom
__global__ void k_soft1(const float* __restrict__ s2t, const int* __restrict__ L,
                        const int* __restrict__ nactp, float* __restrict__ M,
                        float* __restrict__ RD) {
    int nact = *nactp;
    int b = blockIdx.y;
    int u = blockIdx.x * 256 + threadIdx.x;
    const float* S = s2t + (size_t)b * 1048576 + u;
    float m = -3e38f, d = 0.f;
    for (int ai = 0; ai < nact; ++ai) {
        float v = S[(size_t)L[ai] * 1024];
        if (v > m) { d *= expf(10.f * (m - v)); m = v; }
        d += expf(10.f * (v - m));
    }
    int cnt0 = 1024 - nact;
    if (cnt0 > 0) {
        if (m < 0.f) { d *= expf(10.f * m); m = 0.f; }
        d += (float)cnt0 * expf(-10.f * m);
    }
    M[b * 1024 + u] = m;
    RD[b * 1024 + u] = 1.f / d;
}

// CT[b][a*4+bb][c][ai] (f16, ai-stride 256) = BGt[b][2hb-1+a][2wb-1+bb][c], R=L[ai]
__global__ void k_ct(const ush* __restrict__ BGt, const int* __restrict__ L,
                     const int* __restrict__ nactp, ush* __restrict__ CT) {
    int nact = *nactp;
    int KPAD = (nact + 31) & ~31;
    int ab = blockIdx.x, b = blockIdx.y, t = threadIdx.x;
    int a = ab >> 2, bb = ab & 3;
    for (int ai0 = 0; ai0 < KPAD; ai0 += 256) {
        int ai = ai0 + t;
        if (ai >= KPAD) break;
        int ok = 0;
        const ush* srow = nullptr;
        if (ai < nact) {
            int R = L[ai];
            int hb = R >> 5, wb = R & 31;
            int row = 2 * hb - 1 + a, col = 2 * wb - 1 + bb;
            if (row >= 0 && row < 64 && col >= 0 && col < 64) {
                ok = 1;
                srow = BGt + ((size_t)((b * 64 + row) * 64 + col) << 7);
            }
        }
        ush* dst = CT + ((size_t)(b * 16 + ab) << 15) + ai;
#pragma unroll 4
        for (int c = 0; c < 128; ++c)
            dst[(size_t)c << 8] = ok ? srow[c] : (ush)0;
    }
}

// Deconv as parity-class GEMM; weight staging applies exp/denominator inline
#define WSQ 40  // ai-stride (halfs) in WS
__global__ void k_dgemm(const float* __restrict__ s2t, const ush* __restrict__ CT,
                        const int* __restrict__ L, const int* __restrict__ nactp,
                        const float* __restrict__ M, const float* __restrict__ RD,
                        float* __restrict__ y) {
    int nact = *nactp;
    int KPAD = (nact + 31) & ~31;
    int mtile = blockIdx.x, par = blockIdx.y, b = blockIdx.z;
    int a_lo = par >> 1, b_lo = par & 1;
    int P0 = 1 - a_lo, Q0 = 1 - b_lo;
    int pb = P0 + mtile * 4;
    int t = threadIdx.x, wid = t >> 6, lane = t & 63;
    int wc = wid & 1, wp2 = wid >> 1;
    __shared__ ush WS[5 * 33 * WSQ];
    __shared__ int Lsh[32];

    f32x4 acc[4][4];
#pragma unroll
    for (int i = 0; i < 4; ++i)
#pragma unroll
        for (int j = 0; j < 4; ++j) acc[i][j] = (f32x4){0.f, 0.f, 0.f, 0.f};

    for (int k0 = 0; k0 < KPAD; k0 += 32) {
        __syncthreads();
        if (t < 32) Lsh[t] = (k0 + t < nact) ? L[k0 + t] : -1;
        __syncthreads();
        for (int idx = t; idx < 5280; idx += 256) {
            int k = idx / 165, rem = idx - k * 165;
            int pr = rem / 33, qi = rem - pr * 33;
            int p_ = pb - 1 + pr, q_ = Q0 - 1 + qi;
            int R = Lsh[k];
            float w = 0.f;
            if (R >= 0 && (unsigned)p_ < 32u && (unsigned)q_ < 32u) {
                int u_ = q_ * 32 + p_;
                float v = s2t[((size_t)(b * 1024 + R) << 10) + u_];
                w = expf(10.f * (v - M[b * 1024 + u_])) * RD[b * 1024 + u_];
            }
            WS[(pr * 33 + qi) * WSQ + k] = f2h(w);
        }
        __syncthreads();
        int kg = (lane >> 4) * 8;
#pragma unroll
        for (int pp = 0; pp < 2; ++pp)
#pragma unroll
            for (int qq = 0; qq < 2; ++qq) {
                int ab = (a_lo + 2 * pp) * 4 + (b_lo + 2 * qq);
                const ush* Abase = CT + ((size_t)(b * 16 + ab) << 15)
                                 + ((size_t)(wc * 64) << 8) + k0 + kg;
                half8 A[4], B[4];
#pragma unroll
                for (int i = 0; i < 4; ++i)
                    A[i] = *(const half8*)(Abase + ((size_t)(i * 16 + (lane & 15)) << 8));
#pragma unroll
                for (int j = 0; j < 4; ++j) {
                    int pr = wp2 * 2 + (j >> 1) + 1 - pp;
                    int qi = (j & 1) * 16 + (lane & 15) - qq + 1;
                    B[j] = *(const half8*)(WS + (pr * 33 + qi) * WSQ + kg);
                }
#pragma unroll
                for (int i = 0; i < 4; ++i)
#pragma unroll
                    for (int j = 0; j < 4; ++j)
                        acc[i][j] = __builtin_amdgcn_mfma_f32_16x16x32_f16(A[i], B[j], acc[i][j], 0, 0, 0);
            }
    }
    int col = lane & 15, rgrp = (lane >> 4) << 2;
#pragma unroll
    for (int i = 0; i < 4; ++i) {
        int c = wc * 64 + i * 16 + rgrp;
#pragma unroll
        for (int j = 0; j < 4; ++j) {
            int pix = wp2 * 64 + j * 16 + col;
            int p_lo = pb + (pix >> 5);
            int q_lo = Q0 + (pix & 31);
            int oy = 2 * p_lo + a_lo - 1;
            int ox = 2 * q_lo + b_lo - 1;
            float* Y = y + ((size_t)((b * 128 + c) * 64 + oy) << 6) + ox;
            Y[0]        = acc[i][j][0] * 0.25f;
            Y[64 * 64]  = acc[i][j][1] * 0.25f;
            Y[2 * 4096] = acc[i][j][2] * 0.25f;
            Y[3 * 4096] = acc[i][j][3] * 0.25f;
        }
    }
}

extern "C" void kernel_launch(void* const* d_in, const int* in_sizes, int n_in,
                              void* d_out, int out_size, void* d_ws, size_t ws_size,
                              hipStream_t stream) {
    (void)in_sizes; (void)n_in; (void)out_size; (void)ws_size;
    const float* fg   = (const float*)d_in[0];
    const float* bg   = (const float*)d_in[1];
    const float* mask = (const float*)d_in[2];
    float* y = (float*)d_out;
    char* ws = (char*)d_ws;

    ush*   fgh   = (ush*)(ws + OFF_FGH);
    ush*   bgh   = (ush*)(ws + OFF_BGH);
    ush*   bgl   = (ush*)(ws + OFF_BGL);
    ush*   BGt   = (ush*)(ws + OFF_BGT);
    float* rnorm = (float*)(ws + OFF_RN);
    float* Mb    = (float*)(ws + OFF_MM);
    float* RD    = (float*)(ws + OFF_RD);
    int*   Lst   = (int*)(ws + OFF_LIST);
    int*   nact  = (int*)(ws + OFF_NACT);
    float* s0    = (float*)(ws + OFF_S0);
    ush*   CT    = (ush*)(ws + OFF_S0);   // aliases s0 after k_fuse
    float* s2t   = (float*)(ws + OFF_S2);

    k_prep<<<dim3(32, 8), 256, 0, stream>>>(fg, bg, fgh, bgh, bgl);
    k_tr<<<dim3(64, 8), 256, 0, stream>>>(bg, BGt);
    k_eqscan<<<1, 1024, 0, stream>>>(mask, Lst, nact);
    k_ssn<<<dim3(4, 8), 256, 0, stream>>>(bgh, bgl, rnorm);
    k_smfma<<<dim3(8, 8, 8), 256, 0, stream>>>(fgh, bgh, bgl, rnorm, s0);
    k_fuse<<<dim3(4, 32, 8), 256, 0, stream>>>(s0, s2t, Lst, nact);
    k_ct<<<dim3(16, 8), 256, 0, stream>>>(BGt, Lst, nact, CT);
    k_soft1<<<dim3(4, 8), 256, 0, stream>>>(s2t, Lst, nact, Mb, RD);
    k_dgemm<<<dim3(8, 4, 8), 256, 0, stream>>>(s2t, CT, Lst, nact, Mb, RD, y);
}

// Round 6
// 154.676 us; speedup vs baseline: 4.3785x; 1.0639x over previous
//
#include <hip/hip_runtime.h>

typedef _Float16 half8 __attribute__((ext_vector_type(8)));
typedef float f32x4 __attribute__((ext_vector_type(4)));
typedef unsigned short us8 __attribute__((ext_vector_type(8)));
typedef unsigned short ush;
typedef unsigned int uint32;

#define IMGB 295936u   // bytes per padded per-batch image (34*34*128*2)
#define WROW 8704u     // bytes per padded image row (34*128*2)

// workspace byte offsets
#define OFF_FGH  0ull
#define OFF_BGH  2367488ull
#define OFF_BGL  4734976ull
#define OFF_BGT  7102464ull
#define OFF_RN   15491072ull
#define OFF_MM   15523840ull
#define OFF_RD   15556608ull
#define OFF_LIST 15589376ull
#define OFF_NACT 15593472ull
#define OFF_S0   15597568ull   // 32 MB: s0 scores, reused as CT after k_fuse
#define OFF_S2   49152000ull   // 32 MB: s2t (u-relabeled)
#define OFF_WGT2 82706432ull   // 2.5 MB: W2[b][35][35][128] f16 softmax weights
// end 85,215,232 bytes (round 1 proved >= 92.4 MB available)

static __device__ __forceinline__ ush f2h(float f) {
    union { _Float16 h; ush u; } c; c.h = (_Float16)f; return c.u;
}
static __device__ __forceinline__ float h2f(ush u) {
    union { _Float16 h; ush u; } c; c.u = u; return (float)c.h;
}
__device__ __forceinline__ int untr(int v) { return ((v & 31) << 5) | (v >> 5); }

// fg/bg fp32 [b][c][64][64] -> downsampled padded f16 {fg_hi, bg_hi, bg_lo} [b][34][34][128]
__global__ void k_prep(const float* __restrict__ fg, const float* __restrict__ bg,
                       ush* __restrict__ fgh, ush* __restrict__ bgh, ush* __restrict__ bgl) {
    int y = blockIdx.x, b = blockIdx.y, t = threadIdx.x;
    int xq = t & 31, cg = t >> 5;
    __shared__ ush lfh[32][130], lbh[32][130], lbl[32][130];
    for (int c0 = 0; c0 < 128; c0 += 8) {
        int c = c0 + cg;
        int src = ((b * 128 + c) * 64 + 2 * y) * 64 + 2 * xq;
        float vf = fg[src], vb = bg[src];
        _Float16 bh = (_Float16)vb; float br = vb - (float)bh;
        union { _Float16 h; ush u; } c1, c3, c4;
        c1.h = (_Float16)vf; c3.h = bh; c4.h = (_Float16)br;
        lfh[xq][c] = c1.u; lbh[xq][c] = c3.u; lbl[xq][c] = c4.u;
    }
    __syncthreads();
    unsigned base = ((b * 34 + y + 1) * 34 + 1) * 128;  // half index
    for (int k = t; k < 2048; k += 256) {               // uint index
        int x = k >> 6, cp = (k & 63) * 2;
        ((uint32*)(fgh + base))[k] = *(const uint32*)&lfh[x][cp];
        ((uint32*)(bgh + base))[k] = *(const uint32*)&lbh[x][cp];
        ((uint32*)(bgl + base))[k] = *(const uint32*)&lbl[x][cp];
    }
    unsigned cb0 = ((unsigned)(b * 34 + y + 1) * 34) * 64;        // uint index
    if (t < 64) {
        ((uint32*)fgh)[cb0 + t] = 0; ((uint32*)bgh)[cb0 + t] = 0; ((uint32*)bgl)[cb0 + t] = 0;
    } else if (t < 128) {
        unsigned cb1 = cb0 + 33 * 64 + (t - 64);
        ((uint32*)fgh)[cb1] = 0; ((uint32*)bgh)[cb1] = 0; ((uint32*)bgl)[cb1] = 0;
    }
    if (y == 0 || y == 31) {
        int prow = (y == 0) ? 0 : 33;
        unsigned rb = (unsigned)(b * 34 + prow) * 2176;  // uint index
        for (int k = t; k < 2176; k += 256) {
            ((uint32*)fgh)[rb + k] = 0; ((uint32*)bgh)[rb + k] = 0; ((uint32*)bgl)[rb + k] = 0;
        }
    }
}

// BGt[b][y][x][c] (f16) = background[b][c][y][x], full resolution
__global__ void k_tr(const float* __restrict__ bg, ush* __restrict__ BGt) {
    int b = blockIdx.y, y = blockIdx.x, t = threadIdx.x;
    __shared__ float lds[64 * 129];
    int xx = t & 63;
    for (int c0 = 0; c0 < 128; c0 += 4) {
        int c = c0 + (t >> 6);
        lds[xx * 129 + c] = bg[((b * 128 + c) * 64 + y) * 64 + xx];
    }
    __syncthreads();
    uint32* dst = (uint32*)(BGt + (size_t)(b * 64 + y) * 8192);
    for (int j = t; j < 4096; j += 256) {
        int x = j >> 6, cp = (j & 63) * 2;
        uint32 h0 = f2h(lds[x * 129 + cp]);
        uint32 h1 = f2h(lds[x * 129 + cp + 1]);
        dst[j] = h0 | (h1 << 16);
    }
}

// eq flags + deterministic compaction (single block, 1024 threads)
__global__ void k_eqscan(const float* __restrict__ mask, int* __restrict__ L,
                         int* __restrict__ nact) {
    __shared__ int f[1024], sc[1024];
    int l = threadIdx.x;
    int hm = l >> 5, wm = l & 31;
    int any = 0;
    for (int di = -1; di <= 1; ++di)
        for (int dj = -1; dj <= 1; ++dj) {
            int yy = hm + di, xx = wm + dj;
            if (yy >= 0 && yy < 32 && xx >= 0 && xx < 32)
                any |= (mask[(2 * yy) * 64 + 2 * xx] != 0.0f);
        }
    f[l] = !any; sc[l] = f[l];
    __syncthreads();
    for (int off = 1; off < 1024; off <<= 1) {
        int v = (l >= off) ? sc[l - off] : 0;
        __syncthreads();
        sc[l] += v;
        __syncthreads();
    }
    if (f[l]) L[sc[l] - 1] = l;
    if (l == 1023) nact[0] = sc[1023];
}

// merged SS + norm
__global__ void k_ssn(const ush* __restrict__ bgh, const ush* __restrict__ bgl,
                      float* __restrict__ rnorm) {
    int rq = blockIdx.x, b = blockIdx.y, t = threadIdx.x;
    int r0 = rq * 8;
    __shared__ float ssh[10][32];
    for (int idx = t; idx < 320; idx += 256) {
        int row = idx >> 5, xx = idx & 31;
        int gy = r0 - 1 + row;
        float s = 0.f;
        if (gy >= 0 && gy < 32) {
            size_t base = ((size_t)(b * 34 + gy + 1) * 34 + xx + 1) * 128;
            for (int c = 0; c < 128; c += 8) {
                us8 vh = *(const us8*)(bgh + base + c);
                us8 vl = *(const us8*)(bgl + base + c);
#pragma unroll
                for (int j = 0; j < 8; ++j) {
                    float v = h2f(vh[j]) + h2f(vl[j]);
                    s += v * v;
                }
            }
        }
        ssh[row][xx] = s;
    }
    __syncthreads();
    int pr = t >> 5, pc = t & 31;
    float n2 = 0.f;
#pragma unroll
    for (int di = -1; di <= 1; ++di)
#pragma unroll
        for (int dj = -1; dj <= 1; ++dj) {
            int xx = pc + dj;
            if (xx >= 0 && xx < 32) n2 += ssh[pr + 1 + di][xx];
        }
    rnorm[b * 1024 + (r0 + pr) * 32 + pc] = 1.0f / fmaxf(sqrtf(n2), 1e-4f);
}

// MFMA score, c-split stage-once window version (2 phases of 64 ch), 2-pass hi/lo.
__global__ __launch_bounds__(256, 2)
void k_smfma(const ush* __restrict__ fgh, const ush* __restrict__ bgh,
             const ush* __restrict__ bgl, const float* __restrict__ rnorm,
             float* __restrict__ s0) {
    int qt = blockIdx.x, pt = blockIdx.y, b = blockIdx.z;
    int t = threadIdx.x, wid = t >> 6, lane = t & 63;
    int wp = wid >> 1, wq = wid & 1;
    __shared__ ulong2 smem_raw[4992];   // 79872 B: bgh | bgl | fgh half-slabs (26624 each)
    char* smem = (char*)smem_raw;

    const char* base0 = (const char*)bgh + (size_t)b * IMGB + (unsigned)(pt * 4) * WROW;
    const char* base1 = (const char*)bgl + (size_t)b * IMGB + (unsigned)(pt * 4) * WROW;
    const char* base2 = (const char*)fgh + (size_t)b * IMGB + (unsigned)(qt * 4) * WROW;

    f32x4 acc[4][4];
#pragma unroll
    for (int i = 0; i < 4; ++i)
#pragma unroll
        for (int j = 0; j < 4; ++j) acc[i][j] = (f32x4){0.f, 0.f, 0.f, 0.f};

    int r15 = lane & 15, hi2 = lane >> 4;
    for (int ch = 0; ch < 2; ++ch) {
        __syncthreads();
        {
            int pixl = (lane >> 3);
            int sl = lane & 7;
            for (int idx = wid; idx < 78; idx += 4) {
                int a = idx / 26;
                int chunk = idx - a * 26;
                int pix = chunk * 8 + pixl;
                int g = sl ^ (pix & 7);
                const char* sb = (a == 0) ? base0 : (a == 1) ? base1 : base2;
                const char* gp = sb + ((unsigned)pix << 8) + ((unsigned)ch << 7)
                               + ((unsigned)g << 4);
                char* lp = smem + (unsigned)(a * 26624 + chunk * 1024);
                __builtin_amdgcn_global_load_lds(
                    (const __attribute__((address_space(1))) void*)gp,
                    (__attribute__((address_space(3))) void*)lp, 16, 0, 0);
            }
        }
        __syncthreads();

        for (int o = 0; o < 9; ++o) {
            int dy = o / 3, dx = o - 3 * (o / 3);
            int pixB[4], pixA[4];
#pragma unroll
            for (int i = 0; i < 4; ++i) {
                pixB[i] = (wp * 2 + (i >> 1) + dy) * 34 + (i & 1) * 16 + r15 + dx;
                pixA[i] = (wq * 2 + (i >> 1) + dy) * 34 + (i & 1) * 16 + r15 + dx;
            }
#pragma unroll
            for (int cc = 0; cc < 2; ++cc) {
                int g = cc * 4 + hi2;
                half8 bh[4], bl[4], af[4];
#pragma unroll
                for (int i = 0; i < 4; ++i) {
                    unsigned offB = ((unsigned)pixB[i] << 7) + ((unsigned)(g ^ (pixB[i] & 7)) << 4);
                    bh[i] = *(const half8*)(smem + offB);
                    bl[i] = *(const half8*)(smem + 26624 + offB);
                    unsigned offA = ((unsigned)pixA[i] << 7) + ((unsigned)(g ^ (pixA[i] & 7)) << 4);
                    af[i] = *(const half8*)(smem + 53248 + offA);
                }
#pragma unroll
                for (int i = 0; i < 4; ++i)
#pragma unroll
                    for (int j = 0; j < 4; ++j) {
                        acc[i][j] = __builtin_amdgcn_mfma_f32_16x16x32_f16(bh[i], af[j], acc[i][j], 0, 0, 0);
                        acc[i][j] = __builtin_amdgcn_mfma_f32_16x16x32_f16(bl[i], af[j], acc[i][j], 0, 0, 0);
                    }
            }
        }
    }
    int col = lane & 15, rgrp = (lane >> 4) << 2;
#pragma unroll
    for (int i = 0; i < 4; ++i) {
        int Pb = pt * 128 + wp * 64 + i * 16 + rgrp;
        float rn0 = rnorm[b * 1024 + Pb + 0];
        float rn1 = rnorm[b * 1024 + Pb + 1];
        float rn2 = rnorm[b * 1024 + Pb + 2];
        float rn3 = rnorm[b * 1024 + Pb + 3];
#pragma unroll
        for (int j = 0; j < 4; ++j) {
            int Q = qt * 128 + wq * 64 + j * 16 + col;
            float* dst = s0 + ((size_t)(b * 1024 + Pb) << 10) + Q;
            dst[0]    = acc[i][j][0] * rn0;
            dst[1024] = acc[i][j][1] * rn1;
            dst[2048] = acc[i][j][2] * rn2;
            dst[3072] = acc[i][j][3] * rn3;
        }
    }
}

// s2t[b][R][u] = fuse(s0) at T=untr(u)
__global__ void k_fuse(const float* __restrict__ s0, float* __restrict__ s2t,
                       const int* __restrict__ L, const int* __restrict__ nactp) {
    int nact = *nactp;
    int b = blockIdx.z;
    int u = blockIdx.x * 256 + threadIdx.x;
    int T = untr(u);
    const float* S = s0 + (size_t)b * 1048576;
    for (int ai = blockIdx.y; ai < nact; ai += 32) {
        int R = L[ai];
        float acc = 0.f;
#pragma unroll
        for (int k = -1; k <= 1; ++k) {
            int Rk = R + k, Tk = T + k;
            if ((unsigned)Rk < 1024u && (unsigned)Tk < 1024u) {
                int Pr = untr(Rk), Qc = untr(Tk);
#pragma unroll
                for (int j = -1; j <= 1; ++j) {
                    int r = Pr + j, cI = Qc + j;
                    if ((unsigned)r < 1024u && (unsigned)cI < 1024u)
                        acc += S[(size_t)r * 1024 + cI];
                }
            }
        }
        s2t[(size_t)b * 1048576 + (size_t)R * 1024 + u] = acc;
    }
}

// online softmax stats over active R per (b,u)
__global__ void k_soft1(const float* __restrict__ s2t, const int* __restrict__ L,
                        const int* __restrict__ nactp, float* __restrict__ M,
                        float* __restrict__ RD) {
    int nact = *nactp;
    int b = blockIdx.y;
    int u = blockIdx.x * 256 + threadIdx.x;
    const float* S = s2t + (size_t)b * 1048576 + u;
    float m = -3e38f, d = 0.f;
    for (int ai = 0; ai < nact; ++ai) {
        float v = S[(size_t)L[ai] * 1024];
        if (v > m) { d *= expf(10.f * (m - v)); m = v; }
        d += expf(10.f * (v - m));
    }
    int cnt0 = 1024 - nact;
    if (cnt0 > 0) {
        if (m < 0.f) { d *= expf(10.f * m); m = 0.f; }
        d += (float)cnt0 * expf(-10.f * m);
    }
    M[b * 1024 + u] = m;
    RD[b * 1024 + u] = 1.f / d;
}

// CT[b][a*4+bb][c][ai] (f16, ai-stride 256) = BGt[b][2hb-1+a][2wb-1+bb][c], R=L[ai]
__global__ void k_ct(const ush* __restrict__ BGt, const int* __restrict__ L,
                     const int* __restrict__ nactp, ush* __restrict__ CT) {
    int nact = *nactp;
    int KPAD = (nact + 31) & ~31;
    int ab = blockIdx.x, b = blockIdx.y, t = threadIdx.x;
    int a = ab >> 2, bb = ab & 3;
    for (int ai0 = 0; ai0 < KPAD; ai0 += 256) {
        int ai = ai0 + t;
        if (ai >= KPAD) break;
        int ok = 0;
        const ush* srow = nullptr;
        if (ai < nact) {
            int R = L[ai];
            int hb = R >> 5, wb = R & 31;
            int row = 2 * hb - 1 + a, col = 2 * wb - 1 + bb;
            if (row >= 0 && row < 64 && col >= 0 && col < 64) {
                ok = 1;
                srow = BGt + ((size_t)((b * 64 + row) * 64 + col) << 7);
            }
        }
        ush* dst = CT + ((size_t)(b * 16 + ab) << 15) + ai;
#pragma unroll 4
        for (int c = 0; c < 128; ++c)
            dst[(size_t)c << 8] = ok ? srow[c] : (ush)0;
    }
}

// W2[b][p1][q1][128] f16 = softmax weight at (p_=p1-1, q_=q1-1, ai=k); zero borders/tail
__global__ void k_wgt2(const float* __restrict__ s2t, const int* __restrict__ L,
                       const int* __restrict__ nactp, const float* __restrict__ M,
                       const float* __restrict__ RD, ush* __restrict__ W2) {
    int nact = *nactp;
    int idx = blockIdx.x * 256 + threadIdx.x;
    if (idx >= 8 * 35 * 35 * 128) return;
    int k = idx & 127;
    int r = idx >> 7;
    int q1 = r % 35; int r2 = r / 35;
    int p1 = r2 % 35; int b = r2 / 35;
    float w = 0.f;
    if (k < nact && p1 >= 1 && p1 <= 32 && q1 >= 1 && q1 <= 32) {
        int u = (q1 - 1) * 32 + (p1 - 1);
        float v = s2t[((size_t)(b * 1024 + L[k]) << 10) + u];
        w = expf(10.f * (v - M[b * 1024 + u])) * RD[b * 1024 + u];
    }
    W2[idx] = f2h(w);
}

// Deconv parity-class GEMM, barrier-free: A,B frags direct from L2 (k-innermost, zero-padded)
__global__ __launch_bounds__(256, 4)
void k_dgemm(const ush* __restrict__ CT, const ush* __restrict__ W2,
             const int* __restrict__ nactp, float* __restrict__ y) {
    int nact = *nactp;
    int KPAD = (nact + 31) & ~31;   // <= 128 for this input
    int pt2 = blockIdx.x;           // 0..31
    int par = blockIdx.y, b = blockIdx.z;
    int a_lo = par >> 1, b_lo = par & 1;
    int P0 = 1 - a_lo, Q0 = 1 - b_lo;
    int p_lo = P0 + pt2;
    int wid = threadIdx.x >> 6, lane = threadIdx.x & 63;
    int r15 = lane & 15, kg = (lane >> 4) << 3;

    f32x4 acc[2][2];
#pragma unroll
    for (int i = 0; i < 2; ++i)
#pragma unroll
        for (int j = 0; j < 2; ++j) acc[i][j] = (f32x4){0.f, 0.f, 0.f, 0.f};

    for (int k0 = 0; k0 < KPAD; k0 += 32) {
#pragma unroll
        for (int pp = 0; pp < 2; ++pp)
#pragma unroll
            for (int qq = 0; qq < 2; ++qq) {
                int ab = (a_lo + 2 * pp) * 4 + (b_lo + 2 * qq);
                const ush* Ab = CT + ((size_t)(b * 16 + ab) << 15)
                              + ((unsigned)(wid * 32) << 8) + k0 + kg;
                int p1 = p_lo - pp + 1;
                int q1b = Q0 - qq + 1;
                const ush* Bb = W2 + (((size_t)(b * 35 + p1) * 35 + q1b) << 7) + k0 + kg;
                half8 A[2], B[2];
                A[0] = *(const half8*)(Ab + ((unsigned)r15 << 8));
                A[1] = *(const half8*)(Ab + ((unsigned)(16 + r15) << 8));
                B[0] = *(const half8*)(Bb + ((unsigned)r15 << 7));
                B[1] = *(const half8*)(Bb + ((unsigned)(16 + r15) << 7));
#pragma unroll
                for (int i = 0; i < 2; ++i)
#pragma unroll
                    for (int j = 0; j < 2; ++j)
                        acc[i][j] = __builtin_amdgcn_mfma_f32_16x16x32_f16(A[i], B[j], acc[i][j], 0, 0, 0);
            }
    }
    int col = r15, rgrp = (lane >> 4) << 2;
    int oy = 2 * p_lo + a_lo - 1;
#pragma unroll
    for (int i = 0; i < 2; ++i) {
        int c = wid * 32 + i * 16 + rgrp;
#pragma unroll
        for (int j = 0; j < 2; ++j) {
            int q_lo = Q0 + j * 16 + col;
            int ox = 2 * q_lo + b_lo - 1;
            float* Y = y + ((size_t)((b * 128 + c) * 64 + oy) << 6) + ox;
            Y[0]         = acc[i][j][0] * 0.25f;
            Y[4096]      = acc[i][j][1] * 0.25f;
            Y[2 * 4096]  = acc[i][j][2] * 0.25f;
            Y[3 * 4096]  = acc[i][j][3] * 0.25f;
        }
    }
}

extern "C" void kernel_launch(void* const* d_in, const int* in_sizes, int n_in,
                              void* d_out, int out_size, void* d_ws, size_t ws_size,
                              hipStream_t stream) {
    (void)in_sizes; (void)n_in; (void)out_size; (void)ws_size;
    const float* fg   = (const float*)d_in[0];
    const float* bg   = (const float*)d_in[1];
    const float* mask = (const float*)d_in[2];
    float* y = (float*)d_out;
    char* ws = (char*)d_ws;

    ush*   fgh   = (ush*)(ws + OFF_FGH);
    ush*   bgh   = (ush*)(ws + OFF_BGH);
    ush*   bgl   = (ush*)(ws + OFF_BGL);
    ush*   BGt   = (ush*)(ws + OFF_BGT);
    float* rnorm = (float*)(ws + OFF_RN);
    float* Mb    = (float*)(ws + OFF_MM);
    float* RD    = (float*)(ws + OFF_RD);
    int*   Lst   = (int*)(ws + OFF_LIST);
    int*   nact  = (int*)(ws + OFF_NACT);
    float* s0    = (float*)(ws + OFF_S0);
    ush*   CT    = (ush*)(ws + OFF_S0);   // aliases s0 after k_fuse
    float* s2t   = (float*)(ws + OFF_S2);
    ush*   W2    = (ush*)(ws + OFF_WGT2);

    k_prep<<<dim3(32, 8), 256, 0, stream>>>(fg, bg, fgh, bgh, bgl);
    k_tr<<<dim3(64, 8), 256, 0, stream>>>(bg, BGt);
    k_eqscan<<<1, 1024, 0, stream>>>(mask, Lst, nact);
    k_ssn<<<dim3(4, 8), 256, 0, stream>>>(bgh, bgl, rnorm);
    k_smfma<<<dim3(8, 8, 8), 256, 0, stream>>>(fgh, bgh, bgl, rnorm, s0);
    k_fuse<<<dim3(4, 32, 8), 256, 0, stream>>>(s0, s2t, Lst, nact);
    k_ct<<<dim3(16, 8), 256, 0, stream>>>(BGt, Lst, nact, CT);
    k_soft1<<<dim3(4, 8), 256, 0, stream>>>(s2t, Lst, nact, Mb, RD);
    k_wgt2<<<4900, 256, 0, stream>>>(s2t, Lst, nact, Mb, RD, W2);
    k_dgemm<<<dim3(32, 4, 8), 256, 0, stream>>>(CT, W2, nact, y);
}

// Round 8
// 125.215 us; speedup vs baseline: 5.4088x; 1.2353x over previous
//
#include <hip/hip_runtime.h>

typedef _Float16 half8 __attribute__((ext_vector_type(8)));
typedef float f32x4 __attribute__((ext_vector_type(4)));
typedef unsigned short us8 __attribute__((ext_vector_type(8)));
typedef unsigned short ush;
typedef unsigned int uint32;

#define IMGB 295936u   // bytes per padded per-batch image (34*34*128*2)
#define WROW 8704u     // bytes per padded image row (34*128*2)

// workspace byte offsets
#define OFF_FGH  0ull
#define OFF_BGH  2367488ull
#define OFF_BGL  4734976ull
#define OFF_BGT  7102464ull
#define OFF_RN   15491072ull
#define OFF_LIST 15589376ull
#define OFF_NACT 15593472ull
#define OFF_S0   15597568ull   // 32 MB: s0 scores, reused as CT after k_fuse
#define OFF_S2   49152000ull   // 32 MB: s2t (u-relabeled)
#define OFF_WGT2 82706432ull   // 3.1 MB: W2[b][35][35][128] f16 softmax weights
// end ~85.8 MB (round 1 proved >= 92.4 MB available)

static __device__ __forceinline__ ush f2h(float f) {
    union { _Float16 h; ush u; } c; c.h = (_Float16)f; return c.u;
}
static __device__ __forceinline__ float h2f(ush u) {
    union { _Float16 h; ush u; } c; c.u = u; return (float)c.h;
}
__device__ __forceinline__ int untr(int v) { return ((v & 31) << 5) | (v >> 5); }

// Fused: BGt full-res transpose + (even rows) downsampled padded f16 {fgh, bgh, bgl}
__global__ void k_prep2(const float* __restrict__ fg, const float* __restrict__ bg,
                        ush* __restrict__ fgh, ush* __restrict__ bgh,
                        ush* __restrict__ bgl, ush* __restrict__ BGt) {
    int y = blockIdx.x, b = blockIdx.y, t = threadIdx.x;
    __shared__ float lds[64 * 129];
    __shared__ float fls[32 * 129];
    int xx = t & 63;
    for (int c0 = 0; c0 < 128; c0 += 4) {
        int c = c0 + (t >> 6);
        lds[xx * 129 + c] = bg[((b * 128 + c) * 64 + y) * 64 + xx];
    }
    __syncthreads();
    // BGt row
    uint32* dst = (uint32*)(BGt + (size_t)(b * 64 + y) * 8192);
    for (int j = t; j < 4096; j += 256) {
        int x = j >> 6, cp = (j & 63) * 2;
        uint32 h0 = f2h(lds[x * 129 + cp]);
        uint32 h1 = f2h(lds[x * 129 + cp + 1]);
        dst[j] = h0 | (h1 << 16);
    }
    if ((y & 1) != 0) return;
    int yd = y >> 1;
    // stage fg even columns of this row
    {
        int xq = t & 31, cg = t >> 5;
        for (int c0 = 0; c0 < 128; c0 += 8) {
            int c = c0 + cg;
            fls[xq * 129 + c] = fg[((b * 128 + c) * 64 + y) * 64 + 2 * xq];
        }
    }
    __syncthreads();
    unsigned base = ((b * 34 + yd + 1) * 34 + 1) * 128;  // half index
    for (int k = t; k < 2048; k += 256) {                // uint index
        int x = k >> 6, cp = (k & 63) * 2;
        float vb0 = lds[(2 * x) * 129 + cp], vb1 = lds[(2 * x) * 129 + cp + 1];
        float vf0 = fls[x * 129 + cp],       vf1 = fls[x * 129 + cp + 1];
        _Float16 bh0 = (_Float16)vb0, bh1 = (_Float16)vb1;
        float br0 = vb0 - (float)bh0, br1 = vb1 - (float)bh1;
        uint32 f01 = (uint32)f2h(vf0) | ((uint32)f2h(vf1) << 16);
        union { _Float16 h; ush u; } x0, x1;
        x0.h = bh0; x1.h = bh1;
        uint32 b01 = (uint32)x0.u | ((uint32)x1.u << 16);
        uint32 l01 = (uint32)f2h(br0) | ((uint32)f2h(br1) << 16);
        ((uint32*)(fgh + base))[k] = f01;
        ((uint32*)(bgh + base))[k] = b01;
        ((uint32*)(bgl + base))[k] = l01;
    }
    // zero col borders (x=0, x=33) of padded row yd+1
    unsigned cb0 = ((unsigned)(b * 34 + yd + 1) * 34) * 64;  // uint index
    if (t < 64) {
        ((uint32*)fgh)[cb0 + t] = 0; ((uint32*)bgh)[cb0 + t] = 0; ((uint32*)bgl)[cb0 + t] = 0;
    } else if (t < 128) {
        unsigned cb1 = cb0 + 33 * 64 + (t - 64);
        ((uint32*)fgh)[cb1] = 0; ((uint32*)bgh)[cb1] = 0; ((uint32*)bgl)[cb1] = 0;
    }
    // zero full top/bottom padded border rows
    if (yd == 0 || yd == 31) {
        int prow = (yd == 0) ? 0 : 33;
        unsigned rb = (unsigned)(b * 34 + prow) * 2176;  // uint index
        for (int k = t; k < 2176; k += 256) {
            ((uint32*)fgh)[rb + k] = 0; ((uint32*)bgh)[rb + k] = 0; ((uint32*)bgl)[rb + k] = 0;
        }
    }
}

// merged SS+norm (blocks x<4) and eq-flag scan/compaction (block x==4, b==0)
__global__ void k_ssnq(const ush* __restrict__ bgh, const ush* __restrict__ bgl,
                       const float* __restrict__ mask, float* __restrict__ rnorm,
                       int* __restrict__ L, int* __restrict__ nact) {
    int bx = blockIdx.x, b = blockIdx.y, t = threadIdx.x;
    __shared__ float ssh[10][32];
    __shared__ int ps[256];
    if (bx == 4) {
        if (b != 0) return;
        int fl[4], s = 0;
#pragma unroll
        for (int j = 0; j < 4; ++j) {
            int l = t * 4 + j;
            int hm = l >> 5, wm = l & 31;
            int any = 0;
            for (int di = -1; di <= 1; ++di)
                for (int dj = -1; dj <= 1; ++dj) {
                    int yy = hm + di, xxx = wm + dj;
                    if (yy >= 0 && yy < 32 && xxx >= 0 && xxx < 32)
                        any |= (mask[(2 * yy) * 64 + 2 * xxx] != 0.0f);
                }
            fl[j] = !any; s += fl[j];
        }
        ps[t] = s;
        __syncthreads();
        for (int off = 1; off < 256; off <<= 1) {
            int v = (t >= off) ? ps[t - off] : 0;
            __syncthreads();
            ps[t] += v;
            __syncthreads();
        }
        int base = ps[t] - s;
#pragma unroll
        for (int j = 0; j < 4; ++j)
            if (fl[j]) L[base++] = t * 4 + j;
        if (t == 255) nact[0] = ps[255];
        return;
    }
    int r0 = bx * 8;
    for (int idx = t; idx < 320; idx += 256) {
        int row = idx >> 5, xx = idx & 31;
        int gy = r0 - 1 + row;
        float s = 0.f;
        if (gy >= 0 && gy < 32) {
            size_t base = ((size_t)(b * 34 + gy + 1) * 34 + xx + 1) * 128;
            for (int c = 0; c < 128; c += 8) {
                us8 vh = *(const us8*)(bgh + base + c);
                us8 vl = *(const us8*)(bgl + base + c);
#pragma unroll
                for (int j = 0; j < 8; ++j) {
                    float v = h2f(vh[j]) + h2f(vl[j]);
                    s += v * v;
                }
            }
        }
        ssh[row][xx] = s;
    }
    __syncthreads();
    int pr = t >> 5, pc = t & 31;
    float n2 = 0.f;
#pragma unroll
    for (int di = -1; di <= 1; ++di)
#pragma unroll
        for (int dj = -1; dj <= 1; ++dj) {
            int xx = pc + dj;
            if (xx >= 0 && xx < 32) n2 += ssh[pr + 1 + di][xx];
        }
    rnorm[b * 1024 + (r0 + pr) * 32 + pc] = 1.0f / fmaxf(sqrtf(n2), 1e-4f);
}

// MFMA score, c-split stage-once window version (2 phases of 64 ch), 2-pass hi/lo.
__global__ __launch_bounds__(256, 2)
void k_smfma(const ush* __restrict__ fgh, const ush* __restrict__ bgh,
             const ush* __restrict__ bgl, const float* __restrict__ rnorm,
             float* __restrict__ s0) {
    int qt = blockIdx.x, pt = blockIdx.y, b = blockIdx.z;
    int t = threadIdx.x, wid = t >> 6, lane = t & 63;
    int wp = wid >> 1, wq = wid & 1;
    __shared__ ulong2 smem_raw[4992];   // 79872 B: bgh | bgl | fgh half-slabs (26624 each)
    char* smem = (char*)smem_raw;

    const char* base0 = (const char*)bgh + (size_t)b * IMGB + (unsigned)(pt * 4) * WROW;
    const char* base1 = (const char*)bgl + (size_t)b * IMGB + (unsigned)(pt * 4) * WROW;
    const char* base2 = (const char*)fgh + (size_t)b * IMGB + (unsigned)(qt * 4) * WROW;

    f32x4 acc[4][4];
#pragma unroll
    for (int i = 0; i < 4; ++i)
#pragma unroll
        for (int j = 0; j < 4; ++j) acc[i][j] = (f32x4){0.f, 0.f, 0.f, 0.f};

    int r15 = lane & 15, hi2 = lane >> 4;
    for (int ch = 0; ch < 2; ++ch) {
        __syncthreads();
        {
            int pixl = (lane >> 3);
            int sl = lane & 7;
            for (int idx = wid; idx < 78; idx += 4) {
                int a = idx / 26;
                int chunk = idx - a * 26;
                int pix = chunk * 8 + pixl;
                int g = sl ^ (pix & 7);
                const char* sb = (a == 0) ? base0 : (a == 1) ? base1 : base2;
                const char* gp = sb + ((unsigned)pix << 8) + ((unsigned)ch << 7)
                               + ((unsigned)g << 4);
                char* lp = smem + (unsigned)(a * 26624 + chunk * 1024);
                __builtin_amdgcn_global_load_lds(
                    (const __attribute__((address_space(1))) void*)gp,
                    (__attribute__((address_space(3))) void*)lp, 16, 0, 0);
            }
        }
        __syncthreads();

        for (int o = 0; o < 9; ++o) {
            int dy = o / 3, dx = o - 3 * (o / 3);
            int pixB[4], pixA[4];
#pragma unroll
            for (int i = 0; i < 4; ++i) {
                pixB[i] = (wp * 2 + (i >> 1) + dy) * 34 + (i & 1) * 16 + r15 + dx;
                pixA[i] = (wq * 2 + (i >> 1) + dy) * 34 + (i & 1) * 16 + r15 + dx;
            }
#pragma unroll
            for (int cc = 0; cc < 2; ++cc) {
                int g = cc * 4 + hi2;
                half8 bh[4], bl[4], af[4];
#pragma unroll
                for (int i = 0; i < 4; ++i) {
                    unsigned offB = ((unsigned)pixB[i] << 7) + ((unsigned)(g ^ (pixB[i] & 7)) << 4);
                    bh[i] = *(const half8*)(smem + offB);
                    bl[i] = *(const half8*)(smem + 26624 + offB);
                    unsigned offA = ((unsigned)pixA[i] << 7) + ((unsigned)(g ^ (pixA[i] & 7)) << 4);
                    af[i] = *(const half8*)(smem + 53248 + offA);
                }
#pragma unroll
                for (int i = 0; i < 4; ++i)
#pragma unroll
                    for (int j = 0; j < 4; ++j) {
                        acc[i][j] = __builtin_amdgcn_mfma_f32_16x16x32_f16(bh[i], af[j], acc[i][j], 0, 0, 0);
                        acc[i][j] = __builtin_amdgcn_mfma_f32_16x16x32_f16(bl[i], af[j], acc[i][j], 0, 0, 0);
                    }
            }
        }
    }
    int col = lane & 15, rgrp = (lane >> 4) << 2;
#pragma unroll
    for (int i = 0; i < 4; ++i) {
        int Pb = pt * 128 + wp * 64 + i * 16 + rgrp;
        float rn0 = rnorm[b * 1024 + Pb + 0];
        float rn1 = rnorm[b * 1024 + Pb + 1];
        float rn2 = rnorm[b * 1024 + Pb + 2];
        float rn3 = rnorm[b * 1024 + Pb + 3];
#pragma unroll
        for (int j = 0; j < 4; ++j) {
            int Q = qt * 128 + wq * 64 + j * 16 + col;
            float* dst = s0 + ((size_t)(b * 1024 + Pb) << 10) + Q;
            dst[0]    = acc[i][j][0] * rn0;
            dst[1024] = acc[i][j][1] * rn1;
            dst[2048] = acc[i][j][2] * rn2;
            dst[3072] = acc[i][j][3] * rn3;
        }
    }
}

// s2t[b][R][u] = fuse(s0) at T=untr(u)
__global__ void k_fuse(const float* __restrict__ s0, float* __restrict__ s2t,
                       const int* __restrict__ L, const int* __restrict__ nactp) {
    int nact = *nactp;
    int b = blockIdx.z;
    int u = blockIdx.x * 256 + threadIdx.x;
    int T = untr(u);
    const float* S = s0 + (size_t)b * 1048576;
    for (int ai = blockIdx.y; ai < nact; ai += 32) {
        int R = L[ai];
        float acc = 0.f;
#pragma unroll
        for (int k = -1; k <= 1; ++k) {
            int Rk = R + k, Tk = T + k;
            if ((unsigned)Rk < 1024u && (unsigned)Tk < 1024u) {
                int Pr = untr(Rk), Qc = untr(Tk);
#pragma unroll
                for (int j = -1; j <= 1; ++j) {
                    int r = Pr + j, cI = Qc + j;
                    if ((unsigned)r < 1024u && (unsigned)cI < 1024u)
                        acc += S[(size_t)r * 1024 + cI];
                }
            }
        }
        s2t[(size_t)b * 1048576 + (size_t)R * 1024 + u] = acc;
    }
}

// CT[b][a*4+bb][c][ai] (f16, ai-stride 256) = BGt[b][2hb-1+a][2wb-1+bb][c], R=L[ai]
__global__ void k_ct(const ush* __restrict__ BGt, const int* __restrict__ L,
                     const int* __restrict__ nactp, ush* __restrict__ CT) {
    int nact = *nactp;
    int KPAD = (nact + 31) & ~31;
    int ab = blockIdx.x, b = blockIdx.y, t = threadIdx.x;
    int a = ab >> 2, bb = ab & 3;
    for (int ai0 = 0; ai0 < KPAD; ai0 += 256) {
        int ai = ai0 + t;
        if (ai >= KPAD) break;
        int ok = 0;
        const ush* srow = nullptr;
        if (ai < nact) {
            int R = L[ai];
            int hb = R >> 5, wb = R & 31;
            int row = 2 * hb - 1 + a, col = 2 * wb - 1 + bb;
            if (row >= 0 && row < 64 && col >= 0 && col < 64) {
                ok = 1;
                srow = BGt + ((size_t)((b * 64 + row) * 64 + col) << 7);
            }
        }
        ush* dst = CT + ((size_t)(b * 16 + ab) << 15) + ai;
#pragma unroll 4
        for (int c = 0; c < 128; ++c)
            dst[(size_t)c << 8] = ok ? srow[c] : (ush)0;
    }
}

// Fused softmax stats + W2 tile write. Block = (u-chunk of 32, b), 256 threads.
__global__ __launch_bounds__(256)
void k_softw(const float* __restrict__ s2t, const int* __restrict__ L,
             const int* __restrict__ nactp, ush* __restrict__ W2) {
    int uc = blockIdx.x, b = blockIdx.y, t = threadIdx.x;
    int nact = *nactp;
    int u0 = uc * 32;
    __shared__ float sm[32][8], sd[32][8];
    __shared__ float Msh[32], RDsh[32];
    __shared__ ush wt[32][136];
    // Phase A: 8-way partitioned online max/sum per u (coalesced rows of 32 u)
    int part = t >> 5, ul = t & 31;
    {
        const float* S = s2t + (size_t)b * 1048576 + u0 + ul;
        float m = -3e38f, d = 0.f;
        for (int ai = part; ai < nact; ai += 8) {
            float v = S[(size_t)L[ai] << 10];
            if (v > m) { d *= expf(10.f * (m - v)); m = v; }
            d += expf(10.f * (v - m));
        }
        sm[ul][part] = m; sd[ul][part] = d;
    }
    __syncthreads();
    if (t < 32) {
        float mm = -3e38f, dd = 0.f;
#pragma unroll
        for (int p = 0; p < 8; ++p) {
            float m2 = sm[t][p], d2 = sd[t][p];
            if (m2 > mm) { dd *= expf(10.f * (mm - m2)); mm = m2; dd += d2; }
            else dd += d2 * expf(10.f * (m2 - mm));
        }
        int cnt0 = 1024 - nact;
        if (cnt0 > 0) {
            if (mm < 0.f) { dd *= expf(10.f * mm); mm = 0.f; }
            dd += (float)cnt0 * expf(-10.f * mm);
        }
        Msh[t] = mm; RDsh[t] = 1.f / dd;
    }
    __syncthreads();
    // Phase B: 128k x 32u tile, coalesced reads, LDS transpose
    for (int kp = 0; kp < 16; ++kp) {
        int k = kp * 8 + part;
        float w = 0.f;
        if (k < nact) {
            float v = s2t[((size_t)(b * 1024 + L[k]) << 10) + u0 + ul];
            w = expf(10.f * (v - Msh[ul])) * RDsh[ul];
        }
        wt[ul][k] = f2h(w);
    }
    __syncthreads();
    // coalesced W2 row writes: each thread writes a FULL 16-half chunk (fix: was 8)
    {
        int ur = t >> 3, kb = t & 7;
        int uu = u0 + ur;
        int p1 = (uu & 31) + 1, q1 = (uu >> 5) + 1;
        ush* dstr = W2 + (((size_t)(b * 35 + p1) * 35 + q1) << 7) + kb * 16;
        *(half8*)dstr       = *(const half8*)&wt[ur][kb * 16];
        *(half8*)(dstr + 8) = *(const half8*)&wt[ur][kb * 16 + 8];
    }
    // zero ALL rows outside p1,q1 in [1,32] (fix: includes 33, not just {0,34})
    for (int r = uc; r < 1225; r += 32) {
        int p1 = r / 35, q1 = r - p1 * 35;
        if (p1 < 1 || p1 > 32 || q1 < 1 || q1 > 32) {
            uint32* row = (uint32*)(W2 + (((size_t)(b * 35 + p1) * 35 + q1) << 7));
            if (t < 64) row[t] = 0;
        }
    }
}

// Deconv parity-class GEMM, barrier-free: A,B frags direct from L2 (k-innermost, zero-padded)
__global__ __launch_bounds__(256, 4)
void k_dgemm(const ush* __restrict__ CT, const ush* __restrict__ W2,
             const int* __restrict__ nactp, float* __restrict__ y) {
    int nact = *nactp;
    int KPAD = (nact + 31) & ~31;   // <= 128 for this input
    int pt2 = blockIdx.x;           // 0..31
    int par = blockIdx.y, b = blockIdx.z;
    int a_lo = par >> 1, b_lo = par & 1;
    int P0 = 1 - a_lo, Q0 = 1 - b_lo;
    int p_lo = P0 + pt2;
    int wid = threadIdx.x >> 6, lane = threadIdx.x & 63;
    int r15 = lane & 15, kg = (lane >> 4) << 3;

    f32x4 acc[2][2];
#pragma unroll
    for (int i = 0; i < 2; ++i)
#pragma unroll
        for (int j = 0; j < 2; ++j) acc[i][j] = (f32x4){0.f, 0.f, 0.f, 0.f};

    for (int k0 = 0; k0 < KPAD; k0 += 32) {
#pragma unroll
        for (int pp = 0; pp < 2; ++pp)
#pragma unroll
            for (int qq = 0; qq < 2; ++qq) {
                int ab = (a_lo + 2 * pp) * 4 + (b_lo + 2 * qq);
                const ush* Ab = CT + ((size_t)(b * 16 + ab) << 15)
                              + ((unsigned)(wid * 32) << 8) + k0 + kg;
                int p1 = p_lo - pp + 1;
                int q1b = Q0 - qq + 1;
                const ush* Bb = W2 + (((size_t)(b * 35 + p1) * 35 + q1b) << 7) + k0 + kg;
                half8 A[2], B[2];
                A[0] = *(const half8*)(Ab + ((unsigned)r15 << 8));
                A[1] = *(const half8*)(Ab + ((unsigned)(16 + r15) << 8));
                B[0] = *(const half8*)(Bb + ((unsigned)r15 << 7));
                B[1] = *(const half8*)(Bb + ((unsigned)(16 + r15) << 7));
#pragma unroll
                for (int i = 0; i < 2; ++i)
#pragma unroll
                    for (int j = 0; j < 2; ++j)
                        acc[i][j] = __builtin_amdgcn_mfma_f32_16x16x32_f16(A[i], B[j], acc[i][j], 0, 0, 0);
            }
    }
    int col = r15, rgrp = (lane >> 4) << 2;
    int oy = 2 * p_lo + a_lo - 1;
#pragma unroll
    for (int i = 0; i < 2; ++i) {
        int c = wid * 32 + i * 16 + rgrp;
#pragma unroll
        for (int j = 0; j < 2; ++j) {
            int q_lo = Q0 + j * 16 + col;
            int ox = 2 * q_lo + b_lo - 1;
            float* Y = y + ((size_t)((b * 128 + c) * 64 + oy) << 6) + ox;
            Y[0]         = acc[i][j][0] * 0.25f;
            Y[4096]      = acc[i][j][1] * 0.25f;
            Y[2 * 4096]  = acc[i][j][2] * 0.25f;
            Y[3 * 4096]  = acc[i][j][3] * 0.25f;
        }
    }
}

extern "C" void kernel_launch(void* const* d_in, const int* in_sizes, int n_in,
                              void* d_out, int out_size, void* d_ws, size_t ws_size,
                              hipStream_t stream) {
    (void)in_sizes; (void)n_in; (void)out_size; (void)ws_size;
    const float* fg   = (const float*)d_in[0];
    const float* bg   = (const float*)d_in[1];
    const float* mask = (const float*)d_in[2];
    float* y = (float*)d_out;
    char* ws = (char*)d_ws;

    ush*   fgh   = (ush*)(ws + OFF_FGH);
    ush*   bgh   = (ush*)(ws + OFF_BGH);
    ush*   bgl   = (ush*)(ws + OFF_BGL);
    ush*   BGt   = (ush*)(ws + OFF_BGT);
    float* rnorm = (float*)(ws + OFF_RN);
    int*   Lst   = (int*)(ws + OFF_LIST);
    int*   nact  = (int*)(ws + OFF_NACT);
    float* s0    = (float*)(ws + OFF_S0);
    ush*   CT    = (ush*)(ws + OFF_S0);   // aliases s0 after k_fuse
    float* s2t   = (float*)(ws + OFF_S2);
    ush*   W2    = (ush*)(ws + OFF_WGT2);

    k_prep2<<<dim3(64, 8), 256, 0, stream>>>(fg, bg, fgh, bgh, bgl, BGt);
    k_ssnq<<<dim3(5, 8), 256, 0, stream>>>(bgh, bgl, mask, rnorm, Lst, nact);
    k_smfma<<<dim3(8, 8, 8), 256, 0, stream>>>(fgh, bgh, bgl, rnorm, s0);
    k_fuse<<<dim3(4, 32, 8), 256, 0, stream>>>(s0, s2t, Lst, nact);
    k_ct<<<dim3(16, 8), 256, 0, stream>>>(BGt, Lst, nact, CT);
    k_softw<<<dim3(32, 8), 256, 0, stream>>>(s2t, Lst, nact, W2);
    k_dgemm<<<dim3(32, 4, 8), 256, 0, stream>>>(CT, W2, nact, y);
}

// Round 9
// 119.876 us; speedup vs baseline: 5.6497x; 1.0445x over previous
//
#include <hip/hip_runtime.h>

typedef _Float16 half8 __attribute__((ext_vector_type(8)));
typedef float f32x4 __attribute__((ext_vector_type(4)));
typedef unsigned short us8 __attribute__((ext_vector_type(8)));
typedef unsigned short ush;
typedef unsigned int uint32;

#define IMGB 295936u   // bytes per padded per-batch bg image (34*34*128*2)
#define WROW 8704u     // bytes per padded bg image row (34*128*2)

// workspace byte offsets
#define OFF_FGH  0ull          // fgh3[b][ch][g][1156 pix][8 halfs] = 2,367,488 B
#define OFF_BGH  2367488ull
#define OFF_BGL  4734976ull
#define OFF_BGT  7102464ull
#define OFF_RN   15491072ull
#define OFF_LIST 15589376ull
#define OFF_NACT 15593472ull
#define OFF_S0   15597568ull   // 32 MB: s0a partial (ch=0), reused as CT after k_fuse
#define OFF_S2   49152000ull   // 32 MB: s2t (u-relabeled)
#define OFF_WGT2 82706432ull   // 2.5 MB: W2[b][35][35][128] f16 softmax weights
#define OFF_S0B  85215232ull   // 32 MB: s0b partial (ch=1)
// end ~117.8 MB (ws is ~268 MB per harness fill size)

static __device__ __forceinline__ ush f2h(float f) {
    union { _Float16 h; ush u; } c; c.h = (_Float16)f; return c.u;
}
static __device__ __forceinline__ float h2f(ush u) {
    union { _Float16 h; ush u; } c; c.u = u; return (float)c.h;
}
__device__ __forceinline__ int untr(int v) { return ((v & 31) << 5) | (v >> 5); }

// Fused: BGt transpose + (even rows) downsampled padded f16 {fgh3 frag-major, bgh, bgl}
__global__ void k_prep2(const float* __restrict__ fg, const float* __restrict__ bg,
                        ush* __restrict__ fgh3, ush* __restrict__ bgh,
                        ush* __restrict__ bgl, ush* __restrict__ BGt) {
    int y = blockIdx.x, b = blockIdx.y, t = threadIdx.x;
    __shared__ float lds[64 * 129];
    __shared__ float fls[32 * 129];
    int xx = t & 63;
    for (int c0 = 0; c0 < 128; c0 += 4) {
        int c = c0 + (t >> 6);
        lds[xx * 129 + c] = bg[((b * 128 + c) * 64 + y) * 64 + xx];
    }
    __syncthreads();
    // BGt row
    uint32* dst = (uint32*)(BGt + (size_t)(b * 64 + y) * 8192);
    for (int j = t; j < 4096; j += 256) {
        int x = j >> 6, cp = (j & 63) * 2;
        uint32 h0 = f2h(lds[x * 129 + cp]);
        uint32 h1 = f2h(lds[x * 129 + cp + 1]);
        dst[j] = h0 | (h1 << 16);
    }
    if ((y & 1) != 0) return;
    int yd = y >> 1;
    {
        int xq = t & 31, cg = t >> 5;
        for (int c0 = 0; c0 < 128; c0 += 8) {
            int c = c0 + cg;
            fls[xq * 129 + c] = fg[((b * 128 + c) * 64 + y) * 64 + 2 * xq];
        }
    }
    __syncthreads();
    unsigned base = ((b * 34 + yd + 1) * 34 + 1) * 128;  // half index (bg layout)
    for (int k = t; k < 2048; k += 256) {                // uint index
        int x = k >> 6, c = (k & 63) * 2;
        float vb0 = lds[(2 * x) * 129 + c], vb1 = lds[(2 * x) * 129 + c + 1];
        float vf0 = fls[x * 129 + c],       vf1 = fls[x * 129 + c + 1];
        _Float16 bh0 = (_Float16)vb0, bh1 = (_Float16)vb1;
        float br0 = vb0 - (float)bh0, br1 = vb1 - (float)bh1;
        union { _Float16 h; ush u; } x0, x1;
        x0.h = bh0; x1.h = bh1;
        uint32 b01 = (uint32)x0.u | ((uint32)x1.u << 16);
        uint32 l01 = (uint32)f2h(br0) | ((uint32)f2h(br1) << 16);
        ((uint32*)(bgh + base))[k] = b01;
        ((uint32*)(bgl + base))[k] = l01;
        // fg -> fragment-major fgh3
        uint32 f01 = (uint32)f2h(vf0) | ((uint32)f2h(vf1) << 16);
        int ch = c >> 6, g = (c >> 3) & 7, cl = c & 7;
        unsigned pix = (unsigned)(yd + 1) * 34 + (x + 1);
        unsigned ui = (((unsigned)(b * 16 + ch * 8 + g) * 1156 + pix) << 2) + (cl >> 1);
        ((uint32*)fgh3)[ui] = f01;
    }
    // zero col borders (x=0, x=33) of padded row yd+1
    unsigned cb0 = ((unsigned)(b * 34 + yd + 1) * 34) * 64;  // uint index (bg layout)
    if (t < 64) {
        ((uint32*)bgh)[cb0 + t] = 0; ((uint32*)bgl)[cb0 + t] = 0;
    } else if (t < 128) {
        unsigned cb1 = cb0 + 33 * 64 + (t - 64);
        ((uint32*)bgh)[cb1] = 0; ((uint32*)bgl)[cb1] = 0;
    } else if (t < 256) {
        int tt = t - 128;                 // 2 pixels x 16 planes x 4 uints
        unsigned pix = (unsigned)(yd + 1) * 34 + ((tt >> 6) ? 33u : 0u);
        int pl = tt & 63, plane = pl >> 2, w = pl & 3;
        ((uint32*)fgh3)[(((unsigned)(b * 16 + plane) * 1156 + pix) << 2) + w] = 0;
    }
    // zero full top/bottom padded border rows
    if (yd == 0 || yd == 31) {
        int prow = (yd == 0) ? 0 : 33;
        unsigned rb = (unsigned)(b * 34 + prow) * 2176;  // uint index (bg layout)
        for (int k = t; k < 2176; k += 256) {
            ((uint32*)bgh)[rb + k] = 0; ((uint32*)bgl)[rb + k] = 0;
            int plane = k / 136, rem = k - plane * 136;
            unsigned pix = (unsigned)prow * 34 + (rem >> 2);
            ((uint32*)fgh3)[(((unsigned)(b * 16 + plane) * 1156 + pix) << 2) + (rem & 3)] = 0;
        }
    }
}

// merged SS+norm (blocks x<4) and eq-flag scan/compaction (block x==4, b==0)
__global__ void k_ssnq(const ush* __restrict__ bgh, const ush* __restrict__ bgl,
                       const float* __restrict__ mask, float* __restrict__ rnorm,
                       int* __restrict__ L, int* __restrict__ nact) {
    int bx = blockIdx.x, b = blockIdx.y, t = threadIdx.x;
    __shared__ float ssh[10][32];
    __shared__ int ps[256];
    if (bx == 4) {
        if (b != 0) return;
        int fl[4], s = 0;
#pragma unroll
        for (int j = 0; j < 4; ++j) {
            int l = t * 4 + j;
            int hm = l >> 5, wm = l & 31;
            int any = 0;
            for (int di = -1; di <= 1; ++di)
                for (int dj = -1; dj <= 1; ++dj) {
                    int yy = hm + di, xxx = wm + dj;
                    if (yy >= 0 && yy < 32 && xxx >= 0 && xxx < 32)
                        any |= (mask[(2 * yy) * 64 + 2 * xxx] != 0.0f);
                }
            fl[j] = !any; s += fl[j];
        }
        ps[t] = s;
        __syncthreads();
        for (int off = 1; off < 256; off <<= 1) {
            int v = (t >= off) ? ps[t - off] : 0;
            __syncthreads();
            ps[t] += v;
            __syncthreads();
        }
        int base = ps[t] - s;
#pragma unroll
        for (int j = 0; j < 4; ++j)
            if (fl[j]) L[base++] = t * 4 + j;
        if (t == 255) nact[0] = ps[255];
        return;
    }
    int r0 = bx * 8;
    for (int idx = t; idx < 320; idx += 256) {
        int row = idx >> 5, xx = idx & 31;
        int gy = r0 - 1 + row;
        float s = 0.f;
        if (gy >= 0 && gy < 32) {
            size_t base = ((size_t)(b * 34 + gy + 1) * 34 + xx + 1) * 128;
            for (int c = 0; c < 128; c += 8) {
                us8 vh = *(const us8*)(bgh + base + c);
                us8 vl = *(const us8*)(bgl + base + c);
#pragma unroll
                for (int j = 0; j < 8; ++j) {
                    float v = h2f(vh[j]) + h2f(vl[j]);
                    s += v * v;
                }
            }
        }
        ssh[row][xx] = s;
    }
    __syncthreads();
    int pr = t >> 5, pc = t & 31;
    float n2 = 0.f;
#pragma unroll
    for (int di = -1; di <= 1; ++di)
#pragma unroll
        for (int dj = -1; dj <= 1; ++dj) {
            int xx = pc + dj;
            if (xx >= 0 && xx < 32) n2 += ssh[pr + 1 + di][xx];
        }
    rnorm[b * 1024 + (r0 + pr) * 32 + pc] = 1.0f / fmaxf(sqrtf(n2), 1e-4f);
}

// MFMA score: one 64-ch phase per block (z = b*2+ch). B(bg hi/lo) via LDS (53KB),
// A(fg) direct from L2 (fragment-major fgh3). Single barrier; 3 blocks/CU.
__global__ __launch_bounds__(256, 3)
void k_smfma(const ush* __restrict__ fgh3, const ush* __restrict__ bgh,
             const ush* __restrict__ bgl, const float* __restrict__ rnorm,
             float* __restrict__ s0a, float* __restrict__ s0b) {
    int qt = blockIdx.x, pt = blockIdx.y, z = blockIdx.z;
    int b = z >> 1, ch = z & 1;
    int t = threadIdx.x, wid = t >> 6, lane = t & 63;
    int wp = wid >> 1, wq = wid & 1;
    __shared__ ulong2 smem_raw[3328];   // 53248 B: bgh | bgl half-slabs (26624 each)
    char* smem = (char*)smem_raw;

    const char* base0 = (const char*)bgh + (size_t)b * IMGB + (unsigned)(pt * 4) * WROW;
    const char* base1 = (const char*)bgl + (size_t)b * IMGB + (unsigned)(pt * 4) * WROW;

    // stage 2 half-slabs: 26 chunks each
    {
        int pixl = (lane >> 3);
        int sl = lane & 7;
        for (int idx = wid; idx < 52; idx += 4) {
            int a = idx / 26;
            int chunk = idx - a * 26;
            int pix = chunk * 8 + pixl;
            int g = sl ^ (pix & 7);
            const char* sb = a ? base1 : base0;
            const char* gp = sb + ((unsigned)pix << 8) + ((unsigned)ch << 7)
                           + ((unsigned)g << 4);
            char* lp = smem + (unsigned)(a * 26624 + chunk * 1024);
            __builtin_amdgcn_global_load_lds(
                (const __attribute__((address_space(1))) void*)gp,
                (__attribute__((address_space(3))) void*)lp, 16, 0, 0);
        }
    }
    __syncthreads();

    f32x4 acc[4][4];
#pragma unroll
    for (int i = 0; i < 4; ++i)
#pragma unroll
        for (int j = 0; j < 4; ++j) acc[i][j] = (f32x4){0.f, 0.f, 0.f, 0.f};

    int r15 = lane & 15, hi2 = lane >> 4;
    const char* Aimg = (const char*)fgh3
                     + (((size_t)(b * 16 + ch * 8)) * 1156 + (unsigned)(qt * 136)) * 16;
    for (int o = 0; o < 9; ++o) {
        int dy = o / 3, dx = o - 3 * (o / 3);
        int pixB[4], pixA[4];
#pragma unroll
        for (int i = 0; i < 4; ++i) {
            pixB[i] = (wp * 2 + (i >> 1) + dy) * 34 + (i & 1) * 16 + r15 + dx;
            pixA[i] = (wq * 2 + (i >> 1) + dy) * 34 + (i & 1) * 16 + r15 + dx;
        }
#pragma unroll
        for (int cc = 0; cc < 2; ++cc) {
            int g = cc * 4 + hi2;
            half8 bh[4], bl[4], af[4];
#pragma unroll
            for (int i = 0; i < 4; ++i) {
                unsigned offB = ((unsigned)pixB[i] << 7) + ((unsigned)(g ^ (pixB[i] & 7)) << 4);
                bh[i] = *(const half8*)(smem + offB);
                bl[i] = *(const half8*)(smem + 26624 + offB);
                af[i] = *(const half8*)(Aimg + (((size_t)g * 1156 + pixA[i]) << 4));
            }
#pragma unroll
            for (int i = 0; i < 4; ++i)
#pragma unroll
                for (int j = 0; j < 4; ++j) {
                    acc[i][j] = __builtin_amdgcn_mfma_f32_16x16x32_f16(bh[i], af[j], acc[i][j], 0, 0, 0);
                    acc[i][j] = __builtin_amdgcn_mfma_f32_16x16x32_f16(bl[i], af[j], acc[i][j], 0, 0, 0);
                }
        }
    }
    float* s0p = ch ? s0b : s0a;
    int col = lane & 15, rgrp = (lane >> 4) << 2;
#pragma unroll
    for (int i = 0; i < 4; ++i) {
        int Pb = pt * 128 + wp * 64 + i * 16 + rgrp;
        float rn0 = rnorm[b * 1024 + Pb + 0];
        float rn1 = rnorm[b * 1024 + Pb + 1];
        float rn2 = rnorm[b * 1024 + Pb + 2];
        float rn3 = rnorm[b * 1024 + Pb + 3];
#pragma unroll
        for (int j = 0; j < 4; ++j) {
            int Q = qt * 128 + wq * 64 + j * 16 + col;
            float* dst = s0p + ((size_t)(b * 1024 + Pb) << 10) + Q;
            dst[0]    = acc[i][j][0] * rn0;
            dst[1024] = acc[i][j][1] * rn1;
            dst[2048] = acc[i][j][2] * rn2;
            dst[3072] = acc[i][j][3] * rn3;
        }
    }
}

// s2t[b][R][u] = fuse(s0a + s0b) at T=untr(u)
__global__ void k_fuse(const float* __restrict__ s0a, const float* __restrict__ s0b,
                       float* __restrict__ s2t,
                       const int* __restrict__ L, const int* __restrict__ nactp) {
    int nact = *nactp;
    int b = blockIdx.z;
    int u = blockIdx.x * 256 + threadIdx.x;
    int T = untr(u);
    const float* Sa = s0a + (size_t)b * 1048576;
    const float* Sb = s0b + (size_t)b * 1048576;
    for (int ai = blockIdx.y; ai < nact; ai += 32) {
        int R = L[ai];
        float acc = 0.f;
#pragma unroll
        for (int k = -1; k <= 1; ++k) {
            int Rk = R + k, Tk = T + k;
            if ((unsigned)Rk < 1024u && (unsigned)Tk < 1024u) {
                int Pr = untr(Rk), Qc = untr(Tk);
#pragma unroll
                for (int j = -1; j <= 1; ++j) {
                    int r = Pr + j, cI = Qc + j;
                    if ((unsigned)r < 1024u && (unsigned)cI < 1024u) {
                        size_t o = (size_t)r * 1024 + cI;
                        acc += Sa[o] + Sb[o];
                    }
                }
            }
        }
        s2t[(size_t)b * 1048576 + (size_t)R * 1024 + u] = acc;
    }
}

// Merged: CT gather (bx<16) and softmax+W2 (bx>=16)
__global__ __launch_bounds__(256)
void k_ctsw(const ush* __restrict__ BGt, const float* __restrict__ s2t,
            const int* __restrict__ L, const int* __restrict__ nactp,
            ush* __restrict__ CT, ush* __restrict__ W2) {
    int bx = blockIdx.x, b = blockIdx.y, t = threadIdx.x;
    int nact = *nactp;
    __shared__ float sm[32][8], sd[32][8];
    __shared__ float Msh[32], RDsh[32];
    __shared__ ush wt[32][136];
    if (bx < 16) {
        // CT[b][a*4+bb][c][ai] (f16, ai-stride 256) = BGt[b][2hb-1+a][2wb-1+bb][c]
        int KPAD = (nact + 31) & ~31;
        int ab = bx, a = ab >> 2, bb = ab & 3;
        for (int ai0 = 0; ai0 < KPAD; ai0 += 256) {
            int ai = ai0 + t;
            if (ai >= KPAD) break;
            int ok = 0;
            const ush* srow = nullptr;
            if (ai < nact) {
                int R = L[ai];
                int hb = R >> 5, wb = R & 31;
                int row = 2 * hb - 1 + a, col = 2 * wb - 1 + bb;
                if (row >= 0 && row < 64 && col >= 0 && col < 64) {
                    ok = 1;
                    srow = BGt + ((size_t)((b * 64 + row) * 64 + col) << 7);
                }
            }
            ush* dst = CT + ((size_t)(b * 16 + ab) << 15) + ai;
#pragma unroll 4
            for (int c = 0; c < 128; ++c)
                dst[(size_t)c << 8] = ok ? srow[c] : (ush)0;
        }
        return;
    }
    // softmax stats + W2 tile
    int uc = bx - 16;
    int u0 = uc * 32;
    int part = t >> 5, ul = t & 31;
    {
        const float* S = s2t + (size_t)b * 1048576 + u0 + ul;
        float m = -3e38f, d = 0.f;
        for (int ai = part; ai < nact; ai += 8) {
            float v = S[(size_t)L[ai] << 10];
            if (v > m) { d *= expf(10.f * (m - v)); m = v; }
            d += expf(10.f * (v - m));
        }
        sm[ul][part] = m; sd[ul][part] = d;
    }
    __syncthreads();
    if (t < 32) {
        float mm = -3e38f, dd = 0.f;
#pragma unroll
        for (int p = 0; p < 8; ++p) {
            float m2 = sm[t][p], d2 = sd[t][p];
            if (m2 > mm) { dd *= expf(10.f * (mm - m2)); mm = m2; dd += d2; }
            else dd += d2 * expf(10.f * (m2 - mm));
        }
        int cnt0 = 1024 - nact;
        if (cnt0 > 0) {
            if (mm < 0.f) { dd *= expf(10.f * mm); mm = 0.f; }
            dd += (float)cnt0 * expf(-10.f * mm);
        }
        Msh[t] = mm; RDsh[t] = 1.f / dd;
    }
    __syncthreads();
    for (int kp = 0; kp < 16; ++kp) {
        int k = kp * 8 + part;
        float w = 0.f;
        if (k < nact) {
            float v = s2t[((size_t)(b * 1024 + L[k]) << 10) + u0 + ul];
            w = expf(10.f * (v - Msh[ul])) * RDsh[ul];
        }
        wt[ul][k] = f2h(w);
    }
    __syncthreads();
    {
        int ur = t >> 3, kb = t & 7;
        int uu = u0 + ur;
        int p1 = (uu & 31) + 1, q1 = (uu >> 5) + 1;
        ush* dstr = W2 + (((size_t)(b * 35 + p1) * 35 + q1) << 7) + kb * 16;
        *(half8*)dstr       = *(const half8*)&wt[ur][kb * 16];
        *(half8*)(dstr + 8) = *(const half8*)&wt[ur][kb * 16 + 8];
    }
    // zero all W2 rows outside p1,q1 in [1,32]
    for (int r = uc; r < 1225; r += 32) {
        int p1 = r / 35, q1 = r - p1 * 35;
        if (p1 < 1 || p1 > 32 || q1 < 1 || q1 > 32) {
            uint32* row = (uint32*)(W2 + (((size_t)(b * 35 + p1) * 35 + q1) << 7));
            if (t < 64) row[t] = 0;
        }
    }
}

// Deconv parity-class GEMM, barrier-free: A,B frags direct from L2
__global__ __launch_bounds__(256, 4)
void k_dgemm(const ush* __restrict__ CT, const ush* __restrict__ W2,
             const int* __restrict__ nactp, float* __restrict__ y) {
    int nact = *nactp;
    int KPAD = (nact + 31) & ~31;
    int pt2 = blockIdx.x;
    int par = blockIdx.y, b = blockIdx.z;
    int a_lo = par >> 1, b_lo = par & 1;
    int P0 = 1 - a_lo, Q0 = 1 - b_lo;
    int p_lo = P0 + pt2;
    int wid = threadIdx.x >> 6, lane = threadIdx.x & 63;
    int r15 = lane & 15, kg = (lane >> 4) << 3;

    f32x4 acc[2][2];
#pragma unroll
    for (int i = 0; i < 2; ++i)
#pragma unroll
        for (int j = 0; j < 2; ++j) acc[i][j] = (f32x4){0.f, 0.f, 0.f, 0.f};

    for (int k0 = 0; k0 < KPAD; k0 += 32) {
#pragma unroll
        for (int pp = 0; pp < 2; ++pp)
#pragma unroll
            for (int qq = 0; qq < 2; ++qq) {
                int ab = (a_lo + 2 * pp) * 4 + (b_lo + 2 * qq);
                const ush* Ab = CT + ((size_t)(b * 16 + ab) << 15)
                              + ((unsigned)(wid * 32) << 8) + k0 + kg;
                int p1 = p_lo - pp + 1;
                int q1b = Q0 - qq + 1;
                const ush* Bb = W2 + (((size_t)(b * 35 + p1) * 35 + q1b) << 7) + k0 + kg;
                half8 A[2], B[2];
                A[0] = *(const half8*)(Ab + ((unsigned)r15 << 8));
                A[1] = *(const half8*)(Ab + ((unsigned)(16 + r15) << 8));
                B[0] = *(const half8*)(Bb + ((unsigned)r15 << 7));
                B[1] = *(const half8*)(Bb + ((unsigned)(16 + r15) << 7));
#pragma unroll
                for (int i = 0; i < 2; ++i)
#pragma unroll
                    for (int j = 0; j < 2; ++j)
                        acc[i][j] = __builtin_amdgcn_mfma_f32_16x16x32_f16(A[i], B[j], acc[i][j], 0, 0, 0);
            }
    }
    int col = r15, rgrp = (lane >> 4) << 2;
    int oy = 2 * p_lo + a_lo - 1;
#pragma unroll
    for (int i = 0; i < 2; ++i) {
        int c = wid * 32 + i * 16 + rgrp;
#pragma unroll
        for (int j = 0; j < 2; ++j) {
            int q_lo = Q0 + j * 16 + col;
            int ox = 2 * q_lo + b_lo - 1;
            float* Y = y + ((size_t)((b * 128 + c) * 64 + oy) << 6) + ox;
            Y[0]         = acc[i][j][0] * 0.25f;
            Y[4096]      = acc[i][j][1] * 0.25f;
            Y[2 * 4096]  = acc[i][j][2] * 0.25f;
            Y[3 * 4096]  = acc[i][j][3] * 0.25f;
        }
    }
}

extern "C" void kernel_launch(void* const* d_in, const int* in_sizes, int n_in,
                              void* d_out, int out_size, void* d_ws, size_t ws_size,
                              hipStream_t stream) {
    (void)in_sizes; (void)n_in; (void)out_size; (void)ws_size;
    const float* fg   = (const float*)d_in[0];
    const float* bg   = (const float*)d_in[1];
    const float* mask = (const float*)d_in[2];
    float* y = (float*)d_out;
    char* ws = (char*)d_ws;

    ush*   fgh3  = (ush*)(ws + OFF_FGH);
    ush*   bgh   = (ush*)(ws + OFF_BGH);
    ush*   bgl   = (ush*)(ws + OFF_BGL);
    ush*   BGt   = (ush*)(ws + OFF_BGT);
    float* rnorm = (float*)(ws + OFF_RN);
    int*   Lst   = (int*)(ws + OFF_LIST);
    int*   nact  = (int*)(ws + OFF_NACT);
    float* s0a   = (float*)(ws + OFF_S0);
    float* s0b   = (float*)(ws + OFF_S0B);
    ush*   CT    = (ush*)(ws + OFF_S0);   // aliases s0a after k_fuse
    float* s2t   = (float*)(ws + OFF_S2);
    ush*   W2    = (ush*)(ws + OFF_WGT2);

    k_prep2<<<dim3(64, 8), 256, 0, stream>>>(fg, bg, fgh3, bgh, bgl, BGt);
    k_ssnq<<<dim3(5, 8), 256, 0, stream>>>(bgh, bgl, mask, rnorm, Lst, nact);
    k_smfma<<<dim3(8, 8, 16), 256, 0, stream>>>(fgh3, bgh, bgl, rnorm, s0a, s0b);
    k_fuse<<<dim3(4, 32, 8), 256, 0, stream>>>(s0a, s0b, s2t, Lst, nact);
    k_ctsw<<<dim3(48, 8), 256, 0, stream>>>(BGt, s2t, Lst, nact, CT, W2);
    k_dgemm<<<dim3(32, 4, 8), 256, 0, stream>>>(CT, W2, nact, y);
}